// Round 1
// baseline (2502.779 us; speedup 1.0000x reference)
//
#include <hip/hip_runtime.h>
#include <math.h>

#define EPSF 2.220446049250313e-16f

// ---------------- click pyramid ----------------
// cf2 layout: position-major [B][128*128][128ch]
__global__ __launch_bounds__(128) void k_pyr1(const float* __restrict__ click,
    const float* __restrict__ w1, const float* __restrict__ b1,
    const float* __restrict__ w2, const float* __restrict__ b2,
    float* __restrict__ cf2) {
  __shared__ float pool1[8];     // [s][c] : 4 sub-positions x 2 channels
  __shared__ float pooled64[64];
  const int b = blockIdx.y;
  const int p2 = blockIdx.x;           // 0..16383 at 128x128 level
  const int y2 = p2 >> 7, x2 = p2 & 127;
  const int tid = threadIdx.x;
  if (tid < 8) {
    const int s = tid >> 1, c = tid & 1;
    const int sy = s >> 1, sx = s & 1;
    const int row = 4 * y2 + 2 * sy, col = 4 * x2 + 2 * sx;
    const float* base = click + (((size_t)(b * 2 + c)) * 512 + row) * 512 + col;
    pool1[tid] = fmaxf(fmaxf(base[0], base[1]), fmaxf(base[512], base[513]));
  }
  __syncthreads();
  if (tid < 64) {
    const float wa = w1[tid * 2], wb = w1[tid * 2 + 1], bb = b1[tid];
    float v = -3.4e38f;
    #pragma unroll
    for (int s = 0; s < 4; ++s)
      v = fmaxf(v, bb + wa * pool1[s * 2] + wb * pool1[s * 2 + 1]);
    pooled64[tid] = v;
  }
  __syncthreads();
  float acc = b2[tid];
  const float4* wrow = reinterpret_cast<const float4*>(w2 + tid * 64);
  #pragma unroll
  for (int i = 0; i < 16; ++i) {
    float4 w = wrow[i];
    acc += w.x * pooled64[i * 4] + w.y * pooled64[i * 4 + 1] +
           w.z * pooled64[i * 4 + 2] + w.w * pooled64[i * 4 + 3];
  }
  cf2[((size_t)b * 16384 + p2) * 128 + tid] = acc;
}

// cf3 layout: position-major [B][4096][256ch]
__global__ __launch_bounds__(256) void k_pyr2(const float* __restrict__ cf2,
    const float* __restrict__ w3, const float* __restrict__ b3,
    float* __restrict__ cf3) {
  __shared__ float pooled[128];
  const int b = blockIdx.y;
  const int p = blockIdx.x;            // 0..4095 at 64x64 level
  const int y = p >> 6, x = p & 63;
  const int tid = threadIdx.x;
  if (tid < 128) {
    const float* r00 = cf2 + ((size_t)b * 16384 + (2 * y) * 128 + 2 * x) * 128;
    pooled[tid] = fmaxf(fmaxf(r00[tid], r00[128 + tid]),
                        fmaxf(r00[128 * 128 + tid], r00[128 * 129 + tid]));
  }
  __syncthreads();
  float acc = b3[tid];
  const float4* wrow = reinterpret_cast<const float4*>(w3 + tid * 128);
  #pragma unroll
  for (int i = 0; i < 32; ++i) {
    float4 w = wrow[i];
    acc += w.x * pooled[i * 4] + w.y * pooled[i * 4 + 1] +
           w.z * pooled[i * 4 + 2] + w.w * pooled[i * 4 + 3];
  }
  cf3[((size_t)b * 4096 + p) * 256 + tid] = acc;
}

// ---------------- per-pixel stats ----------------
__global__ __launch_bounds__(256) void k_colsums(const float* __restrict__ A,
    const float* __restrict__ Bm,
    float* __restrict__ SA, float* __restrict__ QA,
    float* __restrict__ SB, float* __restrict__ QB) {
  const int b = blockIdx.y;
  const int m = blockIdx.x * 256 + threadIdx.x;
  const float* a = A + ((size_t)b * 256) * 4096 + m;
  const float* bb = Bm + ((size_t)b * 256) * 4096 + m;
  float sa = 0, qa = 0, sb = 0, qb = 0;
  for (int c = 0; c < 256; ++c) {
    float x = a[(size_t)c * 4096];
    sa += x; qa += x * x;
    float y = bb[(size_t)c * 4096];
    sb += y; qb += y * y;
  }
  const int o = b * 4096 + m;
  SA[o] = sa; QA[o] = qa; SB[o] = sb; QB[o] = qb;
}

__global__ __launch_bounds__(256) void k_stats9(const float* __restrict__ SA,
    const float* __restrict__ QA, const float* __restrict__ SB, const float* __restrict__ QB,
    float* __restrict__ muA, float* __restrict__ invA,
    float* __restrict__ muB, float* __restrict__ invB) {
  const int b = blockIdx.y;
  const int m = blockIdx.x * 256 + threadIdx.x;
  const int y = m >> 6, x = m & 63;
  const int base = b * 4096;
  float sa = 0, qa = 0, sb = 0, qb = 0;
  #pragma unroll
  for (int dy = -1; dy <= 1; ++dy) {
    const int yy = y + dy;
    if ((unsigned)yy >= 64u) continue;
    #pragma unroll
    for (int dx = -1; dx <= 1; ++dx) {
      const int xx = x + dx;
      if ((unsigned)xx >= 64u) continue;
      const int idx = base + yy * 64 + xx;
      sa += SA[idx]; qa += QA[idx];
      sb += SB[idx]; qb += QB[idx];
    }
  }
  const float ma = sa * (1.f / 2304.f);
  const float mb = sb * (1.f / 2304.f);
  const float na = sqrtf(fmaxf(qa - 2304.f * ma * ma, 0.f));
  const float nb = sqrtf(fmaxf(qb - 2304.f * mb * mb, 0.f));
  muA[base + m] = ma;
  invA[base + m] = 1.f / (na + EPSF);
  muB[base + m] = mb;
  invB[base + m] = 1.f / (nb + EPSF);
}

// ---------------- G = A^T B  (per batch) ----------------
// G[m,n] = sum_c A[c*4096+m] * B[c*4096+n]
__global__ __launch_bounds__(256) void k_gemm_g(const float* __restrict__ A,
    const float* __restrict__ Bm, float* __restrict__ G) {
  __shared__ float As[16][64];
  __shared__ float Bs[16][64];
  const int tid = threadIdx.x;
  const int tx = tid & 15, ty = tid >> 4;
  const int m0 = blockIdx.y * 64, n0 = blockIdx.x * 64;
  float acc[4][4] = {};
  for (int k0 = 0; k0 < 256; k0 += 16) {
    #pragma unroll
    for (int t = 0; t < 4; ++t) {
      const int e = tid + t * 256;
      const int kk = e >> 6, col = e & 63;
      As[kk][col] = A[(size_t)(k0 + kk) * 4096 + m0 + col];
      Bs[kk][col] = Bm[(size_t)(k0 + kk) * 4096 + n0 + col];
    }
    __syncthreads();
    #pragma unroll
    for (int k = 0; k < 16; ++k) {
      const float4 a4 = *reinterpret_cast<const float4*>(&As[k][ty * 4]);
      const float4 b4 = *reinterpret_cast<const float4*>(&Bs[k][tx * 4]);
      const float av[4] = {a4.x, a4.y, a4.z, a4.w};
      const float bv[4] = {b4.x, b4.y, b4.z, b4.w};
      #pragma unroll
      for (int i = 0; i < 4; ++i)
        #pragma unroll
        for (int j = 0; j < 4; ++j)
          acc[i][j] += av[i] * bv[j];
    }
    __syncthreads();
  }
  #pragma unroll
  for (int i = 0; i < 4; ++i) {
    float4 v = make_float4(acc[i][0], acc[i][1], acc[i][2], acc[i][3]);
    *reinterpret_cast<float4*>(&G[(size_t)(m0 + ty * 4 + i) * 4096 + n0 + tx * 4]) = v;
  }
}

// ---------------- f build from shifted G ----------------
__global__ __launch_bounds__(256) void k_fbuild(const float* __restrict__ G,
    const float* __restrict__ muA, const float* __restrict__ invA,
    const float* __restrict__ muB, const float* __restrict__ invB,
    float* __restrict__ F) {
  const int tid = threadIdx.x;
  const int m = blockIdx.x >> 4;
  const int n = ((blockIdx.x & 15) << 8) + tid;
  const int ym = m >> 6, xm = m & 63, yn = n >> 6, xn = n & 63;
  float acc = 0.f;
  #pragma unroll
  for (int dy = -1; dy <= 1; ++dy) {
    const int ymd = ym + dy, ynd = yn + dy;
    if ((unsigned)ymd < 64u && (unsigned)ynd < 64u) {
      #pragma unroll
      for (int dx = -1; dx <= 1; ++dx) {
        const int xmd = xm + dx, xnd = xn + dx;
        if ((unsigned)xmd < 64u && (unsigned)xnd < 64u) {
          acc += G[(size_t)(ymd * 64 + xmd) * 4096 + (ynd * 64 + xnd)];
        }
      }
    }
  }
  const float v = (acc - 2304.f * muA[m] * muB[n]) * invA[m] * invB[n] * 100.f;
  F[(size_t)m * 4096 + n] = v;
}

// ---------------- row softmax (in place) ----------------
__global__ __launch_bounds__(256) void k_softmax(float* __restrict__ F) {
  __shared__ float redm[4];
  __shared__ float reds[4];
  const int m = blockIdx.x;
  const int tid = threadIdx.x;
  float* row = F + (size_t)m * 4096;
  float v[16];
  float mx = -3.4e38f;
  #pragma unroll
  for (int t = 0; t < 16; ++t) {
    v[t] = row[tid + t * 256];
    mx = fmaxf(mx, v[t]);
  }
  #pragma unroll
  for (int off = 32; off; off >>= 1) mx = fmaxf(mx, __shfl_xor(mx, off));
  const int wave = tid >> 6, lane = tid & 63;
  if (lane == 0) redm[wave] = mx;
  __syncthreads();
  mx = fmaxf(fmaxf(redm[0], redm[1]), fmaxf(redm[2], redm[3]));
  float s = 0.f;
  #pragma unroll
  for (int t = 0; t < 16; ++t) {
    v[t] = __expf(v[t] - mx);
    s += v[t];
  }
  #pragma unroll
  for (int off = 32; off; off >>= 1) s += __shfl_xor(s, off);
  if (lane == 0) reds[wave] = s;
  __syncthreads();
  s = reds[0] + reds[1] + reds[2] + reds[3];
  const float inv = 1.f / s;
  #pragma unroll
  for (int t = 0; t < 16; ++t) row[tid + t * 256] = v[t] * inv;
}

// ---------------- Y = P @ cf^T  (per batch) ----------------
// Y[c,m] = sum_n cf3pm[n*256+c] * F[m*4096+n]
__global__ __launch_bounds__(256) void k_pv(const float* __restrict__ CF,
    const float* __restrict__ F, float* __restrict__ Y) {
  __shared__ float As[16][64];   // [kk][c]
  __shared__ float Bs[16][68];   // [kk][m], padded
  const int tid = threadIdx.x;
  const int tx = tid & 15, ty = tid >> 4;
  const int c0 = blockIdx.y * 64, m0 = blockIdx.x * 64;
  float acc[4][4] = {};
  for (int k0 = 0; k0 < 4096; k0 += 16) {
    #pragma unroll
    for (int t = 0; t < 4; ++t) {
      const int e = tid + t * 256;
      const int kk = e >> 6, col = e & 63;
      As[kk][col] = CF[(size_t)(k0 + kk) * 256 + c0 + col];
    }
    #pragma unroll
    for (int t = 0; t < 4; ++t) {
      const int e = tid + t * 256;
      const int mm = e >> 4, kk = e & 15;
      Bs[kk][mm] = F[(size_t)(m0 + mm) * 4096 + k0 + kk];
    }
    __syncthreads();
    #pragma unroll
    for (int k = 0; k < 16; ++k) {
      const float4 a4 = *reinterpret_cast<const float4*>(&As[k][ty * 4]);
      const float4 b4 = *reinterpret_cast<const float4*>(&Bs[k][tx * 4]);
      const float av[4] = {a4.x, a4.y, a4.z, a4.w};
      const float bv[4] = {b4.x, b4.y, b4.z, b4.w};
      #pragma unroll
      for (int i = 0; i < 4; ++i)
        #pragma unroll
        for (int j = 0; j < 4; ++j)
          acc[i][j] += av[i] * bv[j];
    }
    __syncthreads();
  }
  #pragma unroll
  for (int i = 0; i < 4; ++i) {
    float4 v = make_float4(acc[i][0], acc[i][1], acc[i][2], acc[i][3]);
    *reinterpret_cast<float4*>(&Y[(size_t)(c0 + ty * 4 + i) * 4096 + m0 + tx * 4]) = v;
  }
}

// ---------------- final conv: out[o,m] = bc[o] + sum_k wc[o,k]*X[k,m] ----------------
__global__ __launch_bounds__(256) void k_final(const float* __restrict__ WC,
    const float* __restrict__ bc, const float* __restrict__ BF,
    const float* __restrict__ Y, float* __restrict__ OUT) {
  __shared__ float As[16][68];   // [kk][o], padded (transposed store)
  __shared__ float Bs[16][64];   // [kk][m]
  const int b = blockIdx.z;
  const int tid = threadIdx.x;
  const int tx = tid & 15, ty = tid >> 4;
  const int o0 = blockIdx.y * 64, m0 = blockIdx.x * 64;
  float acc[4][4] = {};
  for (int k0 = 0; k0 < 512; k0 += 16) {
    #pragma unroll
    for (int t = 0; t < 4; ++t) {
      const int e = tid + t * 256;
      const int oo = e >> 4, kk = e & 15;
      As[kk][oo] = WC[(size_t)(o0 + oo) * 512 + k0 + kk];
    }
    #pragma unroll
    for (int t = 0; t < 4; ++t) {
      const int e = tid + t * 256;
      const int kk = e >> 6, col = e & 63;
      const int k = k0 + kk;
      const float* src = (k < 256)
          ? (BF + ((size_t)(b * 256 + k)) * 4096)
          : (Y + ((size_t)(b * 256 + (k - 256))) * 4096);
      Bs[kk][col] = src[m0 + col];
    }
    __syncthreads();
    #pragma unroll
    for (int k = 0; k < 16; ++k) {
      const float4 a4 = *reinterpret_cast<const float4*>(&As[k][ty * 4]);
      const float4 b4 = *reinterpret_cast<const float4*>(&Bs[k][tx * 4]);
      const float av[4] = {a4.x, a4.y, a4.z, a4.w};
      const float bv[4] = {b4.x, b4.y, b4.z, b4.w};
      #pragma unroll
      for (int i = 0; i < 4; ++i)
        #pragma unroll
        for (int j = 0; j < 4; ++j)
          acc[i][j] += av[i] * bv[j];
    }
    __syncthreads();
  }
  #pragma unroll
  for (int i = 0; i < 4; ++i) {
    const int o = o0 + ty * 4 + i;
    const float bias = bc[o];
    float4 v = make_float4(acc[i][0] + bias, acc[i][1] + bias,
                           acc[i][2] + bias, acc[i][3] + bias);
    *reinterpret_cast<float4*>(&OUT[((size_t)(b * 256 + o)) * 4096 + m0 + tx * 4]) = v;
  }
}

extern "C" void kernel_launch(void* const* d_in, const int* in_sizes, int n_in,
                              void* d_out, int out_size, void* d_ws, size_t ws_size,
                              hipStream_t stream) {
  const float* block_fea = (const float*)d_in[0];
  const float* spp       = (const float*)d_in[1];
  const float* click     = (const float*)d_in[2];
  const float* w1 = (const float*)d_in[3];
  const float* b1 = (const float*)d_in[4];
  const float* w2 = (const float*)d_in[5];
  const float* b2 = (const float*)d_in[6];
  const float* w3 = (const float*)d_in[7];
  const float* b3 = (const float*)d_in[8];
  const float* wc = (const float*)d_in[9];
  const float* bc = (const float*)d_in[10];
  float* out = (float*)d_out;

  float* ws = (float*)d_ws;
  float* cf2  = ws;                    // 4*16384*128      =  8388608
  float* cf3  = cf2 + 8388608;         // 4*4096*256       =  4194304
  float* SA   = cf3 + 4194304;         // 4*4096
  float* QA   = SA + 16384;
  float* SB   = QA + 16384;
  float* QB   = SB + 16384;
  float* muA  = QB + 16384;
  float* invA = muA + 16384;
  float* muB  = invA + 16384;
  float* invB = muB + 16384;
  float* G    = invB + 16384;          // 4096*4096        = 16777216
  float* F    = G + 16777216;          // 4096*4096        = 16777216
  float* Y    = F + 16777216;          // 4*256*4096       =  4194304

  k_pyr1<<<dim3(16384, 4), 128, 0, stream>>>(click, w1, b1, w2, b2, cf2);
  k_pyr2<<<dim3(4096, 4), 256, 0, stream>>>(cf2, w3, b3, cf3);
  k_colsums<<<dim3(16, 4), 256, 0, stream>>>(block_fea, spp, SA, QA, SB, QB);
  k_stats9<<<dim3(16, 4), 256, 0, stream>>>(SA, QA, SB, QB, muA, invA, muB, invB);

  for (int b = 0; b < 4; ++b) {
    const float* Ab = block_fea + (size_t)b * 256 * 4096;
    const float* Bb = spp + (size_t)b * 256 * 4096;
    k_gemm_g<<<dim3(64, 64), 256, 0, stream>>>(Ab, Bb, G);
    k_fbuild<<<dim3(65536), 256, 0, stream>>>(G, muA + b * 4096, invA + b * 4096,
                                              muB + b * 4096, invB + b * 4096, F);
    k_softmax<<<dim3(4096), 256, 0, stream>>>(F);
    k_pv<<<dim3(64, 4), 256, 0, stream>>>(cf3 + (size_t)b * 4096 * 256, F,
                                          Y + (size_t)b * 256 * 4096);
  }

  k_final<<<dim3(64, 4, 4), 256, 0, stream>>>(wc, bc, block_fea, Y, out);
}

// Round 3
// 875.094 us; speedup vs baseline: 2.8600x; 2.8600x over previous
//
#include <hip/hip_runtime.h>
#include <math.h>

#define EPSF 2.220446049250313e-16f

typedef short bf16x8 __attribute__((ext_vector_type(8)));
typedef float f32x4 __attribute__((ext_vector_type(4)));

static __device__ __forceinline__ unsigned short f2bf(float x) {
  union { float f; unsigned u; } v; v.f = x;
  unsigned r = v.u + 0x7fffu + ((v.u >> 16) & 1u);
  return (unsigned short)(r >> 16);
}

// ---------------- zero Y ----------------
__global__ __launch_bounds__(256) void k_zero(float* __restrict__ Y) {
  const int t = blockIdx.x * 256 + threadIdx.x;
  #pragma unroll
  for (int i = 0; i < 4; ++i) {
    float4 z = make_float4(0.f, 0.f, 0.f, 0.f);
    *reinterpret_cast<float4*>(&Y[(size_t)(t + i * 262144) * 4]) = z;
  }
}

// ---------------- transpose + cast to bf16 ----------------
// src [R][C] f32 -> dst [C][R] bf16
__global__ __launch_bounds__(256) void k_tcast(const float* __restrict__ src0,
    unsigned short* __restrict__ dst0, int R, int C,
    size_t src_z, size_t dst_z) {
  __shared__ float ld[64][65];
  const float* src = src0 + blockIdx.z * src_z;
  unsigned short* dst = dst0 + blockIdx.z * dst_z;
  const int c0 = blockIdx.x * 64, r0 = blockIdx.y * 64;
  const int t = threadIdx.x;
  const int colr = t & 63, rowr = t >> 6;
  #pragma unroll
  for (int i = 0; i < 16; ++i) {
    const int rl = rowr + i * 4;
    ld[colr][rl] = src[(size_t)(r0 + rl) * C + c0 + colr];
  }
  __syncthreads();
  const int rl = t & 63, clb = t >> 6;
  #pragma unroll
  for (int i = 0; i < 16; ++i) {
    const int cl = clb + i * 4;
    dst[(size_t)(c0 + cl) * R + r0 + rl] = f2bf(ld[cl][rl]);
  }
}

// ---------------- click pyramid ----------------
// cf2 layout: position-major [B][128*128][128ch]; 16 positions per block
__global__ __launch_bounds__(128) void k_pyr1(const float* __restrict__ click,
    const float* __restrict__ w1, const float* __restrict__ b1,
    const float* __restrict__ w2, const float* __restrict__ b2,
    float* __restrict__ cf2) {
  __shared__ float pool1[16][8];
  __shared__ float pooled64[16][64];
  const int b = blockIdx.y;
  const int pg = blockIdx.x;           // group of 16 positions at 128x128 level
  const int tid = threadIdx.x;
  {
    const int q = tid >> 3, s = (tid >> 1) & 3, c = tid & 1;
    const int p2 = pg * 16 + q;
    const int y2 = p2 >> 7, x2 = p2 & 127;
    const int sy = s >> 1, sx = s & 1;
    const int row = 4 * y2 + 2 * sy, col = 4 * x2 + 2 * sx;
    const float* base = click + (((size_t)(b * 2 + c)) * 512 + row) * 512 + col;
    pool1[q][s * 2 + c] = fmaxf(fmaxf(base[0], base[1]), fmaxf(base[512], base[513]));
  }
  __syncthreads();
  {
    const int c1 = tid & 63, qh = tid >> 6;
    const float wa = w1[c1 * 2], wb = w1[c1 * 2 + 1], bb = b1[c1];
    #pragma unroll
    for (int r = 0; r < 8; ++r) {
      const int q = qh * 8 + r;
      float v = -3.4e38f;
      #pragma unroll
      for (int s = 0; s < 4; ++s)
        v = fmaxf(v, bb + wa * pool1[q][s * 2] + wb * pool1[q][s * 2 + 1]);
      pooled64[q][c1] = v;
    }
  }
  __syncthreads();
  float acc[16];
  #pragma unroll
  for (int q = 0; q < 16; ++q) acc[q] = b2[tid];
  const float4* wrow = reinterpret_cast<const float4*>(w2 + tid * 64);
  #pragma unroll
  for (int k4 = 0; k4 < 16; ++k4) {
    const float4 w = wrow[k4];
    #pragma unroll
    for (int q = 0; q < 16; ++q) {
      const float4 p = *reinterpret_cast<const float4*>(&pooled64[q][k4 * 4]);
      acc[q] += w.x * p.x + w.y * p.y + w.z * p.z + w.w * p.w;
    }
  }
  #pragma unroll
  for (int q = 0; q < 16; ++q)
    cf2[((size_t)b * 16384 + pg * 16 + q) * 128 + tid] = acc[q];
}

// cf3 layout: position-major [B][4096][256ch]; 16 positions per block
__global__ __launch_bounds__(256) void k_pyr2(const float* __restrict__ cf2,
    const float* __restrict__ w3, const float* __restrict__ b3,
    float* __restrict__ cf3) {
  __shared__ float pooled[16][128];
  const int b = blockIdx.y;
  const int pb = blockIdx.x;           // group of 16 positions at 64x64 level
  const int tid = threadIdx.x;
  #pragma unroll
  for (int i = 0; i < 8; ++i) {
    const int idx = tid + 256 * i;
    const int q = idx >> 7, c = idx & 127;
    const int p = pb * 16 + q;
    const int y = p >> 6, x = p & 63;
    const size_t r0 = (size_t)b * 16384 + (2 * y) * 128 + 2 * x;
    const float* s0 = cf2 + r0 * 128 + c;
    pooled[q][c] = fmaxf(fmaxf(s0[0], s0[128]), fmaxf(s0[128 * 128], s0[128 * 129]));
  }
  __syncthreads();
  float acc[16];
  #pragma unroll
  for (int q = 0; q < 16; ++q) acc[q] = b3[tid];
  const float4* wrow = reinterpret_cast<const float4*>(w3 + tid * 128);
  #pragma unroll
  for (int k4 = 0; k4 < 32; ++k4) {
    const float4 w = wrow[k4];
    #pragma unroll
    for (int q = 0; q < 16; ++q) {
      const float4 p = *reinterpret_cast<const float4*>(&pooled[q][k4 * 4]);
      acc[q] += w.x * p.x + w.y * p.y + w.z * p.z + w.w * p.w;
    }
  }
  #pragma unroll
  for (int q = 0; q < 16; ++q)
    cf3[((size_t)b * 4096 + pb * 16 + q) * 256 + tid] = acc[q];
}

// ---------------- per-pixel stats ----------------
__global__ __launch_bounds__(256) void k_colsums(const float* __restrict__ A,
    const float* __restrict__ Bm,
    float* __restrict__ SA, float* __restrict__ QA,
    float* __restrict__ SB, float* __restrict__ QB) {
  const int b = blockIdx.y;
  const int m = blockIdx.x * 256 + threadIdx.x;
  const float* a = A + ((size_t)b * 256) * 4096 + m;
  const float* bb = Bm + ((size_t)b * 256) * 4096 + m;
  float sa = 0, qa = 0, sb = 0, qb = 0;
  for (int c = 0; c < 256; ++c) {
    float x = a[(size_t)c * 4096];
    sa += x; qa += x * x;
    float y = bb[(size_t)c * 4096];
    sb += y; qb += y * y;
  }
  const int o = b * 4096 + m;
  SA[o] = sa; QA[o] = qa; SB[o] = sb; QB[o] = qb;
}

__global__ __launch_bounds__(256) void k_stats9(const float* __restrict__ SA,
    const float* __restrict__ QA, const float* __restrict__ SB, const float* __restrict__ QB,
    float* __restrict__ muA, float* __restrict__ invA,
    float* __restrict__ muB, float* __restrict__ invB) {
  const int b = blockIdx.y;
  const int m = blockIdx.x * 256 + threadIdx.x;
  const int y = m >> 6, x = m & 63;
  const int base = b * 4096;
  float sa = 0, qa = 0, sb = 0, qb = 0;
  #pragma unroll
  for (int dy = -1; dy <= 1; ++dy) {
    const int yy = y + dy;
    if ((unsigned)yy >= 64u) continue;
    #pragma unroll
    for (int dx = -1; dx <= 1; ++dx) {
      const int xx = x + dx;
      if ((unsigned)xx >= 64u) continue;
      const int idx = base + yy * 64 + xx;
      sa += SA[idx]; qa += QA[idx];
      sb += SB[idx]; qb += QB[idx];
    }
  }
  const float ma = sa * (1.f / 2304.f);
  const float mb = sb * (1.f / 2304.f);
  const float na = sqrtf(fmaxf(qa - 2304.f * ma * ma, 0.f));
  const float nb = sqrtf(fmaxf(qb - 2304.f * mb * mb, 0.f));
  muA[base + m] = ma;
  invA[base + m] = 1.f / (na + EPSF);
  muB[base + m] = mb;
  invB[base + m] = 1.f / (nb + EPSF);
}

// ---------------- MFMA tile helpers ----------------
// LDS tile: [128 rows][32 k] bf16, 64B rows, 16B chunks XOR-swizzled by (row&3)
static __device__ __forceinline__ void stage_tile(const unsigned short* __restrict__ src,
    size_t srow, int r0, int k0, unsigned short* __restrict__ lds, int tid) {
  #pragma unroll
  for (int p = 0; p < 2; ++p) {
    const int idx = tid + p * 256;
    const int m = idx >> 2, q = idx & 3;
    const bf16x8 v = *reinterpret_cast<const bf16x8*>(src + (size_t)(r0 + m) * srow + k0 + q * 8);
    *reinterpret_cast<bf16x8*>(lds + m * 32 + ((q ^ (m & 3)) * 8)) = v;
  }
}

static __device__ __forceinline__ bf16x8 frag(const unsigned short* __restrict__ lds,
                                              int row, int q) {
  return *reinterpret_cast<const bf16x8*>(lds + row * 32 + ((q ^ (row & 3)) * 8));
}

// ---------------- G = A^T B (per batch), bf16 MFMA ----------------
// At, Bt: [4096 pos][256 c] bf16 (k-minor). G: [4096][4096] f32
__global__ __launch_bounds__(256) void k_gemm_g(const unsigned short* __restrict__ At,
    const unsigned short* __restrict__ Bt, float* __restrict__ G) {
  __shared__ unsigned short As[128 * 32];
  __shared__ unsigned short Bs[128 * 32];
  const int tid = threadIdx.x;
  const int m0 = blockIdx.y * 128, n0 = blockIdx.x * 128;
  const int l = tid & 63, w = tid >> 6;
  const int wr = w >> 1, wc = w & 1;
  const int q = l >> 4, lr = l & 15;
  f32x4 acc[4][4];
  #pragma unroll
  for (int i = 0; i < 4; ++i)
    #pragma unroll
    for (int j = 0; j < 4; ++j)
      acc[i][j] = f32x4{0.f, 0.f, 0.f, 0.f};
  for (int k0 = 0; k0 < 256; k0 += 32) {
    stage_tile(At, 256, m0, k0, As, tid);
    stage_tile(Bt, 256, n0, k0, Bs, tid);
    __syncthreads();
    bf16x8 a[4], bvv[4];
    #pragma unroll
    for (int i = 0; i < 4; ++i) a[i] = frag(As, wr * 64 + i * 16 + lr, q);
    #pragma unroll
    for (int j = 0; j < 4; ++j) bvv[j] = frag(Bs, wc * 64 + j * 16 + lr, q);
    #pragma unroll
    for (int i = 0; i < 4; ++i)
      #pragma unroll
      for (int j = 0; j < 4; ++j)
        acc[i][j] = __builtin_amdgcn_mfma_f32_16x16x32_bf16(a[i], bvv[j], acc[i][j], 0, 0, 0);
    __syncthreads();
  }
  const int rb = 4 * q;
  #pragma unroll
  for (int i = 0; i < 4; ++i)
    #pragma unroll
    for (int j = 0; j < 4; ++j) {
      const size_t base = (size_t)(m0 + wr * 64 + i * 16 + rb) * 4096 + n0 + wc * 64 + j * 16 + lr;
      #pragma unroll
      for (int r = 0; r < 4; ++r)
        G[base + (size_t)r * 4096] = acc[i][j][r];
    }
}

// ---------------- fused fbuild + softmax -> bf16 P ----------------
__global__ __launch_bounds__(256) void k_fsoft(const float* __restrict__ G,
    const float* __restrict__ muA, const float* __restrict__ invA,
    const float* __restrict__ muB, const float* __restrict__ invB,
    unsigned short* __restrict__ P) {
  __shared__ float redm[4];
  __shared__ float reds[4];
  const int m = blockIdx.x;
  const int tid = threadIdx.x;
  const int ym = m >> 6, xm = m & 63;
  float acc[16];
  #pragma unroll
  for (int u = 0; u < 16; ++u) acc[u] = 0.f;
  #pragma unroll
  for (int dy = -1; dy <= 1; ++dy) {
    if ((unsigned)(ym + dy) >= 64u) continue;
    #pragma unroll
    for (int dx = -1; dx <= 1; ++dx) {
      if ((unsigned)(xm + dx) >= 64u) continue;
      const float* Gr = G + (size_t)((ym + dy) * 64 + xm + dx) * 4096 + (dy * 64 + dx);
      #pragma unroll
      for (int u = 0; u < 16; ++u) {
        const int n = tid + u * 256;
        const int yn = n >> 6, xn = n & 63;
        if ((unsigned)(yn + dy) < 64u && (unsigned)(xn + dx) < 64u) acc[u] += Gr[n];
      }
    }
  }
  const float s1 = 2304.f * muA[m];
  const float ia100 = invA[m] * 100.f;
  float mx = -3.4e38f;
  #pragma unroll
  for (int u = 0; u < 16; ++u) {
    const int n = tid + u * 256;
    const float lg = (acc[u] - s1 * muB[n]) * (ia100 * invB[n]);
    acc[u] = lg;
    mx = fmaxf(mx, lg);
  }
  #pragma unroll
  for (int off = 32; off; off >>= 1) mx = fmaxf(mx, __shfl_xor(mx, off));
  const int wave = tid >> 6, lane = tid & 63;
  if (lane == 0) redm[wave] = mx;
  __syncthreads();
  mx = fmaxf(fmaxf(redm[0], redm[1]), fmaxf(redm[2], redm[3]));
  float s = 0.f;
  #pragma unroll
  for (int u = 0; u < 16; ++u) {
    acc[u] = __expf(acc[u] - mx);
    s += acc[u];
  }
  #pragma unroll
  for (int off = 32; off; off >>= 1) s += __shfl_xor(s, off);
  if (lane == 0) reds[wave] = s;
  __syncthreads();
  s = reds[0] + reds[1] + reds[2] + reds[3];
  const float inv = 1.f / s;
  unsigned short* row = P + (size_t)m * 4096;
  #pragma unroll
  for (int u = 0; u < 16; ++u)
    row[tid + u * 256] = f2bf(acc[u] * inv);
}

// ---------------- Y += CF^T x P^T : M=c(256) N=m(4096) K=n, split-K ----------------
// CFt: [256 c][4096 n] bf16; P: [4096 m][4096 n] bf16; Y: [256][4096] f32 (atomic)
__global__ __launch_bounds__(256) void k_pv(const unsigned short* __restrict__ CFt,
    const unsigned short* __restrict__ P, float* __restrict__ Y) {
  __shared__ unsigned short As[128 * 32];
  __shared__ unsigned short Bs[128 * 32];
  const int tid = threadIdx.x;
  const int c0 = blockIdx.y * 128, mb0 = blockIdx.x * 128;
  const int kbase = blockIdx.z * 512;
  const int l = tid & 63, w = tid >> 6;
  const int wr = w >> 1, wc = w & 1;
  const int q = l >> 4, lr = l & 15;
  f32x4 acc[4][4];
  #pragma unroll
  for (int i = 0; i < 4; ++i)
    #pragma unroll
    for (int j = 0; j < 4; ++j)
      acc[i][j] = f32x4{0.f, 0.f, 0.f, 0.f};
  for (int ks = 0; ks < 512; ks += 32) {
    const int k0 = kbase + ks;
    stage_tile(CFt, 4096, c0, k0, As, tid);
    stage_tile(P, 4096, mb0, k0, Bs, tid);
    __syncthreads();
    bf16x8 a[4], bvv[4];
    #pragma unroll
    for (int i = 0; i < 4; ++i) a[i] = frag(As, wr * 64 + i * 16 + lr, q);
    #pragma unroll
    for (int j = 0; j < 4; ++j) bvv[j] = frag(Bs, wc * 64 + j * 16 + lr, q);
    #pragma unroll
    for (int i = 0; i < 4; ++i)
      #pragma unroll
      for (int j = 0; j < 4; ++j)
        acc[i][j] = __builtin_amdgcn_mfma_f32_16x16x32_bf16(a[i], bvv[j], acc[i][j], 0, 0, 0);
    __syncthreads();
  }
  const int rb = 4 * q;
  #pragma unroll
  for (int i = 0; i < 4; ++i)
    #pragma unroll
    for (int j = 0; j < 4; ++j) {
      #pragma unroll
      for (int r = 0; r < 4; ++r) {
        const size_t o = (size_t)(c0 + wr * 64 + i * 16 + rb + r) * 4096 + mb0 + wc * 64 + j * 16 + lr;
        atomicAdd(&Y[o], acc[i][j][r]);
      }
    }
}

// ---------------- final conv: out[o,m] = bc[o] + sum_k wc[o,k]*X[k,m] ----------------
__global__ __launch_bounds__(256) void k_final(const float* __restrict__ WC,
    const float* __restrict__ bc, const float* __restrict__ BF,
    const float* __restrict__ Y, float* __restrict__ OUT) {
  __shared__ float As[16][68];
  __shared__ float Bs[16][64];
  const int b = blockIdx.z;
  const int tid = threadIdx.x;
  const int tx = tid & 15, ty = tid >> 4;
  const int o0 = blockIdx.y * 64, m0 = blockIdx.x * 64;
  float acc[4][4] = {};
  for (int k0 = 0; k0 < 512; k0 += 16) {
    #pragma unroll
    for (int t = 0; t < 4; ++t) {
      const int e = tid + t * 256;
      const int oo = e >> 4, kk = e & 15;
      As[kk][oo] = WC[(size_t)(o0 + oo) * 512 + k0 + kk];
    }
    #pragma unroll
    for (int t = 0; t < 4; ++t) {
      const int e = tid + t * 256;
      const int kk = e >> 6, col = e & 63;
      const int k = k0 + kk;
      const float* src = (k < 256)
          ? (BF + ((size_t)(b * 256 + k)) * 4096)
          : (Y + ((size_t)(b * 256 + (k - 256))) * 4096);
      Bs[kk][col] = src[m0 + col];
    }
    __syncthreads();
    #pragma unroll
    for (int k = 0; k < 16; ++k) {
      const float4 a4 = *reinterpret_cast<const float4*>(&As[k][ty * 4]);
      const float4 b4 = *reinterpret_cast<const float4*>(&Bs[k][tx * 4]);
      const float av[4] = {a4.x, a4.y, a4.z, a4.w};
      const float bv[4] = {b4.x, b4.y, b4.z, b4.w};
      #pragma unroll
      for (int i = 0; i < 4; ++i)
        #pragma unroll
        for (int j = 0; j < 4; ++j)
          acc[i][j] += av[i] * bv[j];
    }
    __syncthreads();
  }
  #pragma unroll
  for (int i = 0; i < 4; ++i) {
    const int o = o0 + ty * 4 + i;
    const float bias = bc[o];
    float4 v = make_float4(acc[i][0] + bias, acc[i][1] + bias,
                           acc[i][2] + bias, acc[i][3] + bias);
    *reinterpret_cast<float4*>(&OUT[((size_t)(b * 256 + o)) * 4096 + m0 + tx * 4]) = v;
  }
}

extern "C" void kernel_launch(void* const* d_in, const int* in_sizes, int n_in,
                              void* d_out, int out_size, void* d_ws, size_t ws_size,
                              hipStream_t stream) {
  const float* block_fea = (const float*)d_in[0];
  const float* spp       = (const float*)d_in[1];
  const float* click     = (const float*)d_in[2];
  const float* w1 = (const float*)d_in[3];
  const float* b1 = (const float*)d_in[4];
  const float* w2 = (const float*)d_in[5];
  const float* b2 = (const float*)d_in[6];
  const float* w3 = (const float*)d_in[7];
  const float* b3 = (const float*)d_in[8];
  const float* wc = (const float*)d_in[9];
  const float* bc = (const float*)d_in[10];
  float* out = (float*)d_out;

  float* ws = (float*)d_ws;
  const size_t M1 = 1024 * 1024;
  float* G    = ws;                         // 16M f (cf2 aliases first 8M f)
  float* cf2  = ws;                         // alias: dead before G is written
  unsigned short* Pb  = (unsigned short*)(ws + 16 * M1);   // 16M ushort (8M f)
  unsigned short* At  = (unsigned short*)(ws + 24 * M1);   // 4M ushort (2M f)
  unsigned short* Bt  = (unsigned short*)(ws + 26 * M1);   // 4M ushort (2M f)
  unsigned short* CFt = (unsigned short*)(ws + 28 * M1);   // 4M ushort (2M f)
  float* cf3  = ws + 30 * M1;               // 4M f
  float* Y    = ws + 34 * M1;               // 4M f
  float* SA   = ws + 38 * M1;
  float* QA   = SA + 16384;
  float* SB   = QA + 16384;
  float* QB   = SB + 16384;
  float* muA  = QB + 16384;
  float* invA = muA + 16384;
  float* muB  = invA + 16384;
  float* invB = muB + 16384;

  k_zero<<<dim3(1024), 256, 0, stream>>>(Y);
  k_pyr1<<<dim3(1024, 4), 128, 0, stream>>>(click, w1, b1, w2, b2, cf2);
  k_pyr2<<<dim3(256, 4), 256, 0, stream>>>(cf2, w3, b3, cf3);
  // transposed bf16 casts: [256][4096] -> [4096][256]
  k_tcast<<<dim3(64, 4, 4), 256, 0, stream>>>(block_fea, At, 256, 4096,
                                              (size_t)256 * 4096, (size_t)4096 * 256);
  k_tcast<<<dim3(64, 4, 4), 256, 0, stream>>>(spp, Bt, 256, 4096,
                                              (size_t)256 * 4096, (size_t)4096 * 256);
  // cf3 [4096][256] -> CFt [256][4096]
  k_tcast<<<dim3(4, 64, 4), 256, 0, stream>>>(cf3, CFt, 4096, 256,
                                              (size_t)4096 * 256, (size_t)256 * 4096);
  k_colsums<<<dim3(16, 4), 256, 0, stream>>>(block_fea, spp, SA, QA, SB, QB);
  k_stats9<<<dim3(16, 4), 256, 0, stream>>>(SA, QA, SB, QB, muA, invA, muB, invB);

  for (int b = 0; b < 4; ++b) {
    const unsigned short* Atb = At + (size_t)b * 4096 * 256;
    const unsigned short* Btb = Bt + (size_t)b * 4096 * 256;
    k_gemm_g<<<dim3(32, 32), 256, 0, stream>>>(Atb, Btb, G);
    k_fsoft<<<dim3(4096), 256, 0, stream>>>(G, muA + b * 4096, invA + b * 4096,
                                            muB + b * 4096, invB + b * 4096, Pb);
    k_pv<<<dim3(32, 2, 8), 256, 0, stream>>>(CFt + (size_t)b * 256 * 4096, Pb,
                                             Y + (size_t)b * 256 * 4096);
  }

  k_final<<<dim3(64, 4, 4), 256, 0, stream>>>(wc, bc, block_fea, Y, out);
}

// Round 4
// 777.448 us; speedup vs baseline: 3.2192x; 1.1256x over previous
//
#include <hip/hip_runtime.h>
#include <math.h>

#define EPSF 2.220446049250313e-16f

typedef short bf16x8 __attribute__((ext_vector_type(8)));
typedef float f32x4 __attribute__((ext_vector_type(4)));

static __device__ __forceinline__ unsigned short f2bf(float x) {
  union { float f; unsigned u; } v; v.f = x;
  unsigned r = v.u + 0x7fffu + ((v.u >> 16) & 1u);
  return (unsigned short)(r >> 16);
}

// ---------------- grid-stride zero ----------------
__global__ __launch_bounds__(256) void k_zero(float* __restrict__ p) {
  const int t = blockIdx.x * 256 + threadIdx.x;
  float4 z = make_float4(0.f, 0.f, 0.f, 0.f);
  *reinterpret_cast<float4*>(&p[(size_t)t * 4]) = z;
}

// ---------------- transpose + cast to bf16 (+ optional col stats) ----------------
// src [R][C] f32 -> dst [C][R] bf16; if SA!=null also accumulate per-column
// (over R) sum and sumsq into SA/QA[blockIdx.z*4096 + col]
__global__ __launch_bounds__(256) void k_tcast(const float* __restrict__ src0,
    unsigned short* __restrict__ dst0, int R, int C,
    size_t src_z, size_t dst_z, float* __restrict__ SA, float* __restrict__ QA) {
  __shared__ float ld[64][65];
  const float* src = src0 + blockIdx.z * src_z;
  unsigned short* dst = dst0 + blockIdx.z * dst_z;
  const int c0 = blockIdx.x * 64, r0 = blockIdx.y * 64;
  const int t = threadIdx.x;
  const int colr = t & 63, rowr = t >> 6;
  float s = 0.f, q = 0.f;
  #pragma unroll
  for (int i = 0; i < 16; ++i) {
    const int rl = rowr + i * 4;
    const float v = src[(size_t)(r0 + rl) * C + c0 + colr];
    ld[colr][rl] = v;
    s += v; q += v * v;
  }
  if (SA) {
    atomicAdd(&SA[blockIdx.z * 4096 + c0 + colr], s);
    atomicAdd(&QA[blockIdx.z * 4096 + c0 + colr], q);
  }
  __syncthreads();
  const int rl = t & 63, clb = t >> 6;
  #pragma unroll
  for (int i = 0; i < 16; ++i) {
    const int cl = clb + i * 4;
    dst[(size_t)(c0 + cl) * R + r0 + rl] = f2bf(ld[cl][rl]);
  }
}

// ---------------- click pyramid ----------------
__global__ __launch_bounds__(128) void k_pyr1(const float* __restrict__ click,
    const float* __restrict__ w1, const float* __restrict__ b1,
    const float* __restrict__ w2, const float* __restrict__ b2,
    float* __restrict__ cf2) {
  __shared__ float pool1[16][8];
  __shared__ float pooled64[16][64];
  const int b = blockIdx.y;
  const int pg = blockIdx.x;
  const int tid = threadIdx.x;
  {
    const int q = tid >> 3, s = (tid >> 1) & 3, c = tid & 1;
    const int p2 = pg * 16 + q;
    const int y2 = p2 >> 7, x2 = p2 & 127;
    const int sy = s >> 1, sx = s & 1;
    const int row = 4 * y2 + 2 * sy, col = 4 * x2 + 2 * sx;
    const float* base = click + (((size_t)(b * 2 + c)) * 512 + row) * 512 + col;
    pool1[q][s * 2 + c] = fmaxf(fmaxf(base[0], base[1]), fmaxf(base[512], base[513]));
  }
  __syncthreads();
  {
    const int c1 = tid & 63, qh = tid >> 6;
    const float wa = w1[c1 * 2], wb = w1[c1 * 2 + 1], bb = b1[c1];
    #pragma unroll
    for (int r = 0; r < 8; ++r) {
      const int q = qh * 8 + r;
      float v = -3.4e38f;
      #pragma unroll
      for (int s = 0; s < 4; ++s)
        v = fmaxf(v, bb + wa * pool1[q][s * 2] + wb * pool1[q][s * 2 + 1]);
      pooled64[q][c1] = v;
    }
  }
  __syncthreads();
  float acc[16];
  #pragma unroll
  for (int q = 0; q < 16; ++q) acc[q] = b2[tid];
  const float4* wrow = reinterpret_cast<const float4*>(w2 + tid * 64);
  #pragma unroll
  for (int k4 = 0; k4 < 16; ++k4) {
    const float4 w = wrow[k4];
    #pragma unroll
    for (int q = 0; q < 16; ++q) {
      const float4 p = *reinterpret_cast<const float4*>(&pooled64[q][k4 * 4]);
      acc[q] += w.x * p.x + w.y * p.y + w.z * p.z + w.w * p.w;
    }
  }
  #pragma unroll
  for (int q = 0; q < 16; ++q)
    cf2[((size_t)b * 16384 + pg * 16 + q) * 128 + tid] = acc[q];
}

__global__ __launch_bounds__(256) void k_pyr2(const float* __restrict__ cf2,
    const float* __restrict__ w3, const float* __restrict__ b3,
    float* __restrict__ cf3) {
  __shared__ float pooled[16][128];
  const int b = blockIdx.y;
  const int pb = blockIdx.x;
  const int tid = threadIdx.x;
  #pragma unroll
  for (int i = 0; i < 8; ++i) {
    const int idx = tid + 256 * i;
    const int q = idx >> 7, c = idx & 127;
    const int p = pb * 16 + q;
    const int y = p >> 6, x = p & 63;
    const size_t r0 = (size_t)b * 16384 + (2 * y) * 128 + 2 * x;
    const float* s0 = cf2 + r0 * 128 + c;
    pooled[q][c] = fmaxf(fmaxf(s0[0], s0[128]), fmaxf(s0[128 * 128], s0[128 * 129]));
  }
  __syncthreads();
  float acc[16];
  #pragma unroll
  for (int q = 0; q < 16; ++q) acc[q] = b3[tid];
  const float4* wrow = reinterpret_cast<const float4*>(w3 + tid * 128);
  #pragma unroll
  for (int k4 = 0; k4 < 32; ++k4) {
    const float4 w = wrow[k4];
    #pragma unroll
    for (int q = 0; q < 16; ++q) {
      const float4 p = *reinterpret_cast<const float4*>(&pooled[q][k4 * 4]);
      acc[q] += w.x * p.x + w.y * p.y + w.z * p.z + w.w * p.w;
    }
  }
  #pragma unroll
  for (int q = 0; q < 16; ++q)
    cf3[((size_t)b * 4096 + pb * 16 + q) * 256 + tid] = acc[q];
}

// ---------------- 9-neighborhood stats ----------------
__global__ __launch_bounds__(256) void k_stats9(const float* __restrict__ SA,
    const float* __restrict__ QA, const float* __restrict__ SB, const float* __restrict__ QB,
    float* __restrict__ muA, float* __restrict__ invA,
    float* __restrict__ muB, float* __restrict__ invB) {
  const int b = blockIdx.y;
  const int m = blockIdx.x * 256 + threadIdx.x;
  const int y = m >> 6, x = m & 63;
  const int base = b * 4096;
  float sa = 0, qa = 0, sb = 0, qb = 0;
  #pragma unroll
  for (int dy = -1; dy <= 1; ++dy) {
    const int yy = y + dy;
    if ((unsigned)yy >= 64u) continue;
    #pragma unroll
    for (int dx = -1; dx <= 1; ++dx) {
      const int xx = x + dx;
      if ((unsigned)xx >= 64u) continue;
      const int idx = base + yy * 64 + xx;
      sa += SA[idx]; qa += QA[idx];
      sb += SB[idx]; qb += QB[idx];
    }
  }
  const float ma = sa * (1.f / 2304.f);
  const float mb = sb * (1.f / 2304.f);
  const float na = sqrtf(fmaxf(qa - 2304.f * ma * ma, 0.f));
  const float nb = sqrtf(fmaxf(qb - 2304.f * mb * mb, 0.f));
  muA[base + m] = ma;
  invA[base + m] = 1.f / (na + EPSF);
  muB[base + m] = mb;
  invB[base + m] = 1.f / (nb + EPSF);
}

// ---------------- MFMA tile helpers ----------------
// LDS tile: [128 rows][40 k-slots] bf16 (80 B row stride -> 2-way bank spread, free)
#define ROWP 40
static __device__ __forceinline__ void stage_tile(const unsigned short* __restrict__ src,
    size_t srow, int r0, int k0, unsigned short* __restrict__ lds, int tid) {
  #pragma unroll
  for (int p = 0; p < 2; ++p) {
    const int idx = tid + p * 256;
    const int m = idx >> 2, q = idx & 3;
    const bf16x8 v = *reinterpret_cast<const bf16x8*>(src + (size_t)(r0 + m) * srow + k0 + q * 8);
    *reinterpret_cast<bf16x8*>(lds + m * ROWP + q * 8) = v;
  }
}

static __device__ __forceinline__ bf16x8 frag(const unsigned short* __restrict__ lds,
                                              int row, int q) {
  return *reinterpret_cast<const bf16x8*>(lds + row * ROWP + q * 8);
}

// ---------------- G = A^T B (per batch), bf16 MFMA ----------------
__global__ __launch_bounds__(256) void k_gemm_g(const unsigned short* __restrict__ At,
    const unsigned short* __restrict__ Bt, float* __restrict__ G) {
  __shared__ unsigned short As[128 * ROWP];
  __shared__ unsigned short Bs[128 * ROWP];
  const int tid = threadIdx.x;
  // XCD-chunked swizzle: each XCD gets 4 consecutive m-tile rows
  const int lin = blockIdx.y * 32 + blockIdx.x;
  const int nlin = ((lin & 7) << 7) | (lin >> 3);
  const int m0 = (nlin >> 5) * 128, n0 = (nlin & 31) * 128;
  const int l = tid & 63, w = tid >> 6;
  const int wr = w >> 1, wc = w & 1;
  const int q = l >> 4, lr = l & 15;
  f32x4 acc[4][4];
  #pragma unroll
  for (int i = 0; i < 4; ++i)
    #pragma unroll
    for (int j = 0; j < 4; ++j)
      acc[i][j] = f32x4{0.f, 0.f, 0.f, 0.f};
  for (int k0 = 0; k0 < 256; k0 += 32) {
    stage_tile(At, 256, m0, k0, As, tid);
    stage_tile(Bt, 256, n0, k0, Bs, tid);
    __syncthreads();
    bf16x8 a[4], bvv[4];
    #pragma unroll
    for (int i = 0; i < 4; ++i) a[i] = frag(As, wr * 64 + i * 16 + lr, q);
    #pragma unroll
    for (int j = 0; j < 4; ++j) bvv[j] = frag(Bs, wc * 64 + j * 16 + lr, q);
    #pragma unroll
    for (int i = 0; i < 4; ++i)
      #pragma unroll
      for (int j = 0; j < 4; ++j)
        acc[i][j] = __builtin_amdgcn_mfma_f32_16x16x32_bf16(a[i], bvv[j], acc[i][j], 0, 0, 0);
    __syncthreads();
  }
  const int rb = 4 * q;
  #pragma unroll
  for (int i = 0; i < 4; ++i)
    #pragma unroll
    for (int j = 0; j < 4; ++j) {
      const size_t base = (size_t)(m0 + wr * 64 + i * 16 + rb) * 4096 + n0 + wc * 64 + j * 16 + lr;
      #pragma unroll
      for (int r = 0; r < 4; ++r)
        G[base + (size_t)r * 4096] = acc[i][j][r];
    }
}

// ---------------- fused fbuild + softmax -> bf16 P ----------------
__global__ __launch_bounds__(256) void k_fsoft(const float* __restrict__ G,
    const float* __restrict__ muA, const float* __restrict__ invA,
    const float* __restrict__ muB, const float* __restrict__ invB,
    unsigned short* __restrict__ P) {
  __shared__ float redm[4];
  __shared__ float reds[4];
  // XCD-chunked swizzle: XCD k processes contiguous m-range [k*512,(k+1)*512)
  // -> concurrent blocks share a ~3 MB sliding window of G rows (fits L2)
  const int m = ((blockIdx.x & 7) << 9) | (blockIdx.x >> 3);
  const int tid = threadIdx.x;
  const int ym = m >> 6, xm = m & 63;
  float acc[16];
  #pragma unroll
  for (int u = 0; u < 16; ++u) acc[u] = 0.f;
  #pragma unroll
  for (int dy = -1; dy <= 1; ++dy) {
    if ((unsigned)(ym + dy) >= 64u) continue;
    #pragma unroll
    for (int dx = -1; dx <= 1; ++dx) {
      if ((unsigned)(xm + dx) >= 64u) continue;
      const float* Gr = G + (size_t)((ym + dy) * 64 + xm + dx) * 4096 + (dy * 64 + dx);
      #pragma unroll
      for (int u = 0; u < 16; ++u) {
        const int n = tid + u * 256;
        const int yn = n >> 6, xn = n & 63;
        if ((unsigned)(yn + dy) < 64u && (unsigned)(xn + dx) < 64u) acc[u] += Gr[n];
      }
    }
  }
  const float s1 = 2304.f * muA[m];
  const float ia100 = invA[m] * 100.f;
  float mx = -3.4e38f;
  #pragma unroll
  for (int u = 0; u < 16; ++u) {
    const int n = tid + u * 256;
    const float lg = (acc[u] - s1 * muB[n]) * (ia100 * invB[n]);
    acc[u] = lg;
    mx = fmaxf(mx, lg);
  }
  #pragma unroll
  for (int off = 32; off; off >>= 1) mx = fmaxf(mx, __shfl_xor(mx, off));
  const int wave = tid >> 6, lane = tid & 63;
  if (lane == 0) redm[wave] = mx;
  __syncthreads();
  mx = fmaxf(fmaxf(redm[0], redm[1]), fmaxf(redm[2], redm[3]));
  float s = 0.f;
  #pragma unroll
  for (int u = 0; u < 16; ++u) {
    acc[u] = __expf(acc[u] - mx);
    s += acc[u];
  }
  #pragma unroll
  for (int off = 32; off; off >>= 1) s += __shfl_xor(s, off);
  if (lane == 0) reds[wave] = s;
  __syncthreads();
  s = reds[0] + reds[1] + reds[2] + reds[3];
  const float inv = 1.f / s;
  unsigned short* row = P + (size_t)m * 4096;
  #pragma unroll
  for (int u = 0; u < 16; ++u)
    row[tid + u * 256] = f2bf(acc[u] * inv);
}

// ---------------- Y += CF^T x P^T : M=c(256) N=m(4096) K=n, split-K ----------------
__global__ __launch_bounds__(256) void k_pv(const unsigned short* __restrict__ CFt,
    const unsigned short* __restrict__ P, float* __restrict__ Y) {
  __shared__ unsigned short As[128 * ROWP];
  __shared__ unsigned short Bs[128 * ROWP];
  const int tid = threadIdx.x;
  const int c0 = blockIdx.y * 128, mb0 = blockIdx.x * 128;
  const int kbase = blockIdx.z * 512;
  const int l = tid & 63, w = tid >> 6;
  const int wr = w >> 1, wc = w & 1;
  const int q = l >> 4, lr = l & 15;
  f32x4 acc[4][4];
  #pragma unroll
  for (int i = 0; i < 4; ++i)
    #pragma unroll
    for (int j = 0; j < 4; ++j)
      acc[i][j] = f32x4{0.f, 0.f, 0.f, 0.f};
  for (int ks = 0; ks < 512; ks += 32) {
    const int k0 = kbase + ks;
    stage_tile(CFt, 4096, c0, k0, As, tid);
    stage_tile(P, 4096, mb0, k0, Bs, tid);
    __syncthreads();
    bf16x8 a[4], bvv[4];
    #pragma unroll
    for (int i = 0; i < 4; ++i) a[i] = frag(As, wr * 64 + i * 16 + lr, q);
    #pragma unroll
    for (int j = 0; j < 4; ++j) bvv[j] = frag(Bs, wc * 64 + j * 16 + lr, q);
    #pragma unroll
    for (int i = 0; i < 4; ++i)
      #pragma unroll
      for (int j = 0; j < 4; ++j)
        acc[i][j] = __builtin_amdgcn_mfma_f32_16x16x32_bf16(a[i], bvv[j], acc[i][j], 0, 0, 0);
    __syncthreads();
  }
  const int rb = 4 * q;
  #pragma unroll
  for (int i = 0; i < 4; ++i)
    #pragma unroll
    for (int j = 0; j < 4; ++j) {
      #pragma unroll
      for (int r = 0; r < 4; ++r) {
        const size_t o = (size_t)(c0 + wr * 64 + i * 16 + rb + r) * 4096 + mb0 + wc * 64 + j * 16 + lr;
        atomicAdd(&Y[o], acc[i][j][r]);
      }
    }
}

// ---------------- final conv ----------------
__global__ __launch_bounds__(256) void k_final(const float* __restrict__ WC,
    const float* __restrict__ bc, const float* __restrict__ BF,
    const float* __restrict__ Y, float* __restrict__ OUT) {
  __shared__ float As[16][68];
  __shared__ float Bs[16][64];
  const int b = blockIdx.z;
  const int tid = threadIdx.x;
  const int tx = tid & 15, ty = tid >> 4;
  const int o0 = blockIdx.y * 64, m0 = blockIdx.x * 64;
  float acc[4][4] = {};
  for (int k0 = 0; k0 < 512; k0 += 16) {
    #pragma unroll
    for (int t = 0; t < 4; ++t) {
      const int e = tid + t * 256;
      const int oo = e >> 4, kk = e & 15;
      As[kk][oo] = WC[(size_t)(o0 + oo) * 512 + k0 + kk];
    }
    #pragma unroll
    for (int t = 0; t < 4; ++t) {
      const int e = tid + t * 256;
      const int kk = e >> 6, col = e & 63;
      const int k = k0 + kk;
      const float* src = (k < 256)
          ? (BF + ((size_t)(b * 256 + k)) * 4096)
          : (Y + ((size_t)(b * 256 + (k - 256))) * 4096);
      Bs[kk][col] = src[m0 + col];
    }
    __syncthreads();
    #pragma unroll
    for (int k = 0; k < 16; ++k) {
      const float4 a4 = *reinterpret_cast<const float4*>(&As[k][ty * 4]);
      const float4 b4 = *reinterpret_cast<const float4*>(&Bs[k][tx * 4]);
      const float av[4] = {a4.x, a4.y, a4.z, a4.w};
      const float bv[4] = {b4.x, b4.y, b4.z, b4.w};
      #pragma unroll
      for (int i = 0; i < 4; ++i)
        #pragma unroll
        for (int j = 0; j < 4; ++j)
          acc[i][j] += av[i] * bv[j];
    }
    __syncthreads();
  }
  #pragma unroll
  for (int i = 0; i < 4; ++i) {
    const int o = o0 + ty * 4 + i;
    const float bias = bc[o];
    float4 v = make_float4(acc[i][0] + bias, acc[i][1] + bias,
                           acc[i][2] + bias, acc[i][3] + bias);
    *reinterpret_cast<float4*>(&OUT[((size_t)(b * 256 + o)) * 4096 + m0 + tx * 4]) = v;
  }
}

extern "C" void kernel_launch(void* const* d_in, const int* in_sizes, int n_in,
                              void* d_out, int out_size, void* d_ws, size_t ws_size,
                              hipStream_t stream) {
  const float* block_fea = (const float*)d_in[0];
  const float* spp       = (const float*)d_in[1];
  const float* click     = (const float*)d_in[2];
  const float* w1 = (const float*)d_in[3];
  const float* b1 = (const float*)d_in[4];
  const float* w2 = (const float*)d_in[5];
  const float* b2 = (const float*)d_in[6];
  const float* w3 = (const float*)d_in[7];
  const float* b3 = (const float*)d_in[8];
  const float* wc = (const float*)d_in[9];
  const float* bc = (const float*)d_in[10];
  float* out = (float*)d_out;

  float* ws = (float*)d_ws;
  const size_t M1 = 1024 * 1024;
  float* G    = ws;                         // 16M f (cf2 aliases first 8M f)
  float* cf2  = ws;                         // alias: dead before G is written
  unsigned short* Pb  = (unsigned short*)(ws + 16 * M1);   // 16M ushort
  unsigned short* At  = (unsigned short*)(ws + 24 * M1);   // 4M ushort
  unsigned short* Bt  = (unsigned short*)(ws + 26 * M1);   // 4M ushort
  unsigned short* CFt = (unsigned short*)(ws + 28 * M1);   // 4M ushort
  float* cf3  = ws + 30 * M1;               // 4M f
  float* Y    = ws + 34 * M1;               // 4M f
  float* SA   = ws + 38 * M1;               // stats: contiguous after Y
  float* QA   = SA + 16384;
  float* SB   = QA + 16384;
  float* QB   = SB + 16384;
  float* muA  = QB + 16384;
  float* invA = muA + 16384;
  float* muB  = invA + 16384;
  float* invB = muB + 16384;

  // zero Y (4M floats) + SA..QB (64K floats) in one contiguous launch
  k_zero<<<dim3(4160), 256, 0, stream>>>(Y);   // covers 4,259,840 floats
  k_pyr1<<<dim3(1024, 4), 128, 0, stream>>>(click, w1, b1, w2, b2, cf2);
  k_pyr2<<<dim3(256, 4), 256, 0, stream>>>(cf2, w3, b3, cf3);
  // transposed bf16 casts (+ fused column stats for A and B)
  k_tcast<<<dim3(64, 4, 4), 256, 0, stream>>>(block_fea, At, 256, 4096,
                                              (size_t)256 * 4096, (size_t)4096 * 256, SA, QA);
  k_tcast<<<dim3(64, 4, 4), 256, 0, stream>>>(spp, Bt, 256, 4096,
                                              (size_t)256 * 4096, (size_t)4096 * 256, SB, QB);
  k_tcast<<<dim3(4, 64, 4), 256, 0, stream>>>(cf3, CFt, 4096, 256,
                                              (size_t)4096 * 256, (size_t)256 * 4096,
                                              (float*)nullptr, (float*)nullptr);
  k_stats9<<<dim3(16, 4), 256, 0, stream>>>(SA, QA, SB, QB, muA, invA, muB, invB);

  for (int b = 0; b < 4; ++b) {
    const unsigned short* Atb = At + (size_t)b * 4096 * 256;
    const unsigned short* Btb = Bt + (size_t)b * 4096 * 256;
    k_gemm_g<<<dim3(32, 32), 256, 0, stream>>>(Atb, Btb, G);
    k_fsoft<<<dim3(4096), 256, 0, stream>>>(G, muA + b * 4096, invA + b * 4096,
                                            muB + b * 4096, invB + b * 4096, Pb);
    k_pv<<<dim3(32, 2, 8), 256, 0, stream>>>(CFt + (size_t)b * 256 * 4096, Pb,
                                             Y + (size_t)b * 256 * 4096);
  }

  k_final<<<dim3(64, 4, 4), 256, 0, stream>>>(wc, bc, block_fea, Y, out);
}

// Round 6
// 625.125 us; speedup vs baseline: 4.0036x; 1.2437x over previous
//
#include <hip/hip_runtime.h>
#include <math.h>

#define EPSF 2.220446049250313e-16f

typedef short bf16x8 __attribute__((ext_vector_type(8)));
typedef float f32x4 __attribute__((ext_vector_type(4)));

static __device__ __forceinline__ unsigned short f2bf(float x) {
  union { float f; unsigned u; } v; v.f = x;
  unsigned r = v.u + 0x7fffu + ((v.u >> 16) & 1u);
  return (unsigned short)(r >> 16);
}

// ---------------- grid-stride zero ----------------
__global__ __launch_bounds__(256) void k_zero(float* __restrict__ p) {
  const int t = blockIdx.x * 256 + threadIdx.x;
  float4 z = make_float4(0.f, 0.f, 0.f, 0.f);
  *reinterpret_cast<float4*>(&p[(size_t)t * 4]) = z;
}

// ---------------- transpose + cast to bf16 (+ optional col stats) ----------------
__global__ __launch_bounds__(256) void k_tcast(const float* __restrict__ src0,
    unsigned short* __restrict__ dst0, int R, int C,
    size_t src_z, size_t dst_z, float* __restrict__ SA, float* __restrict__ QA) {
  __shared__ float ld[64][65];
  const float* src = src0 + blockIdx.z * src_z;
  unsigned short* dst = dst0 + blockIdx.z * dst_z;
  const int c0 = blockIdx.x * 64, r0 = blockIdx.y * 64;
  const int t = threadIdx.x;
  const int colr = t & 63, rowr = t >> 6;
  float s = 0.f, q = 0.f;
  #pragma unroll
  for (int i = 0; i < 16; ++i) {
    const int rl = rowr + i * 4;
    const float v = src[(size_t)(r0 + rl) * C + c0 + colr];
    ld[colr][rl] = v;
    s += v; q += v * v;
  }
  if (SA) {
    atomicAdd(&SA[blockIdx.z * 4096 + c0 + colr], s);
    atomicAdd(&QA[blockIdx.z * 4096 + c0 + colr], q);
  }
  __syncthreads();
  const int rl = t & 63, clb = t >> 6;
  #pragma unroll
  for (int i = 0; i < 16; ++i) {
    const int cl = clb + i * 4;
    dst[(size_t)(c0 + cl) * R + r0 + rl] = f2bf(ld[cl][rl]);
  }
}

// ---------------- click pyramid ----------------
__global__ __launch_bounds__(128) void k_pyr1(const float* __restrict__ click,
    const float* __restrict__ w1, const float* __restrict__ b1,
    const float* __restrict__ w2, const float* __restrict__ b2,
    float* __restrict__ cf2) {
  __shared__ float pool1[16][8];
  __shared__ float pooled64[16][64];
  const int b = blockIdx.y;
  const int pg = blockIdx.x;
  const int tid = threadIdx.x;
  {
    const int q = tid >> 3, s = (tid >> 1) & 3, c = tid & 1;
    const int p2 = pg * 16 + q;
    const int y2 = p2 >> 7, x2 = p2 & 127;
    const int sy = s >> 1, sx = s & 1;
    const int row = 4 * y2 + 2 * sy, col = 4 * x2 + 2 * sx;
    const float* base = click + (((size_t)(b * 2 + c)) * 512 + row) * 512 + col;
    pool1[q][s * 2 + c] = fmaxf(fmaxf(base[0], base[1]), fmaxf(base[512], base[513]));
  }
  __syncthreads();
  {
    const int c1 = tid & 63, qh = tid >> 6;
    const float wa = w1[c1 * 2], wb = w1[c1 * 2 + 1], bb = b1[c1];
    #pragma unroll
    for (int r = 0; r < 8; ++r) {
      const int q = qh * 8 + r;
      float v = -3.4e38f;
      #pragma unroll
      for (int s = 0; s < 4; ++s)
        v = fmaxf(v, bb + wa * pool1[q][s * 2] + wb * pool1[q][s * 2 + 1]);
      pooled64[q][c1] = v;
    }
  }
  __syncthreads();
  float acc[16];
  #pragma unroll
  for (int q = 0; q < 16; ++q) acc[q] = b2[tid];
  const float4* wrow = reinterpret_cast<const float4*>(w2 + tid * 64);
  #pragma unroll
  for (int k4 = 0; k4 < 16; ++k4) {
    const float4 w = wrow[k4];
    #pragma unroll
    for (int q = 0; q < 16; ++q) {
      const float4 p = *reinterpret_cast<const float4*>(&pooled64[q][k4 * 4]);
      acc[q] += w.x * p.x + w.y * p.y + w.z * p.z + w.w * p.w;
    }
  }
  #pragma unroll
  for (int q = 0; q < 16; ++q)
    cf2[((size_t)b * 16384 + pg * 16 + q) * 128 + tid] = acc[q];
}

__global__ __launch_bounds__(256) void k_pyr2(const float* __restrict__ cf2,
    const float* __restrict__ w3, const float* __restrict__ b3,
    float* __restrict__ cf3) {
  __shared__ float pooled[16][128];
  const int b = blockIdx.y;
  const int pb = blockIdx.x;
  const int tid = threadIdx.x;
  #pragma unroll
  for (int i = 0; i < 8; ++i) {
    const int idx = tid + 256 * i;
    const int q = idx >> 7, c = idx & 127;
    const int p = pb * 16 + q;
    const int y = p >> 6, x = p & 63;
    const size_t r0 = (size_t)b * 16384 + (2 * y) * 128 + 2 * x;
    const float* s0 = cf2 + r0 * 128 + c;
    pooled[q][c] = fmaxf(fmaxf(s0[0], s0[128]), fmaxf(s0[128 * 128], s0[128 * 129]));
  }
  __syncthreads();
  float acc[16];
  #pragma unroll
  for (int q = 0; q < 16; ++q) acc[q] = b3[tid];
  const float4* wrow = reinterpret_cast<const float4*>(w3 + tid * 128);
  #pragma unroll
  for (int k4 = 0; k4 < 32; ++k4) {
    const float4 w = wrow[k4];
    #pragma unroll
    for (int q = 0; q < 16; ++q) {
      const float4 p = *reinterpret_cast<const float4*>(&pooled[q][k4 * 4]);
      acc[q] += w.x * p.x + w.y * p.y + w.z * p.z + w.w * p.w;
    }
  }
  #pragma unroll
  for (int q = 0; q < 16; ++q)
    cf3[((size_t)b * 4096 + pb * 16 + q) * 256 + tid] = acc[q];
}

// ---------------- 9-neighborhood stats ----------------
__global__ __launch_bounds__(256) void k_stats9(const float* __restrict__ SA,
    const float* __restrict__ QA, const float* __restrict__ SB, const float* __restrict__ QB,
    float* __restrict__ muA, float* __restrict__ invA,
    float* __restrict__ muB, float* __restrict__ invB) {
  const int b = blockIdx.y;
  const int m = blockIdx.x * 256 + threadIdx.x;
  const int y = m >> 6, x = m & 63;
  const int base = b * 4096;
  float sa = 0, qa = 0, sb = 0, qb = 0;
  #pragma unroll
  for (int dy = -1; dy <= 1; ++dy) {
    const int yy = y + dy;
    if ((unsigned)yy >= 64u) continue;
    #pragma unroll
    for (int dx = -1; dx <= 1; ++dx) {
      const int xx = x + dx;
      if ((unsigned)xx >= 64u) continue;
      const int idx = base + yy * 64 + xx;
      sa += SA[idx]; qa += QA[idx];
      sb += SB[idx]; qb += QB[idx];
    }
  }
  const float ma = sa * (1.f / 2304.f);
  const float mb = sb * (1.f / 2304.f);
  const float na = sqrtf(fmaxf(qa - 2304.f * ma * ma, 0.f));
  const float nb = sqrtf(fmaxf(qb - 2304.f * mb * mb, 0.f));
  muA[base + m] = ma;
  invA[base + m] = 1.f / (na + EPSF);
  muB[base + m] = mb;
  invB[base + m] = 1.f / (nb + EPSF);
}

// ---------------- MFMA tile helpers ----------------
#define ROWP 40
static __device__ __forceinline__ void stage_tile(const unsigned short* __restrict__ src,
    size_t srow, int r0, int k0, unsigned short* __restrict__ lds, int tid) {
  #pragma unroll
  for (int p = 0; p < 2; ++p) {
    const int idx = tid + p * 256;
    const int m = idx >> 2, q = idx & 3;
    const bf16x8 v = *reinterpret_cast<const bf16x8*>(src + (size_t)(r0 + m) * srow + k0 + q * 8);
    *reinterpret_cast<bf16x8*>(lds + m * ROWP + q * 8) = v;
  }
}

static __device__ __forceinline__ bf16x8 frag(const unsigned short* __restrict__ lds,
                                              int row, int q) {
  return *reinterpret_cast<const bf16x8*>(lds + row * ROWP + q * 8);
}

// ---------------- G = A^T B (per batch), bf16 MFMA ----------------
__global__ __launch_bounds__(256) void k_gemm_g(const unsigned short* __restrict__ At,
    const unsigned short* __restrict__ Bt, float* __restrict__ G) {
  __shared__ unsigned short As[128 * ROWP];
  __shared__ unsigned short Bs[128 * ROWP];
  const int tid = threadIdx.x;
  const int lin = blockIdx.y * 32 + blockIdx.x;
  const int nlin = ((lin & 7) << 7) | (lin >> 3);
  const int m0 = (nlin >> 5) * 128, n0 = (nlin & 31) * 128;
  const int l = tid & 63, w = tid >> 6;
  const int wr = w >> 1, wc = w & 1;
  const int q = l >> 4, lr = l & 15;
  f32x4 acc[4][4];
  #pragma unroll
  for (int i = 0; i < 4; ++i)
    #pragma unroll
    for (int j = 0; j < 4; ++j)
      acc[i][j] = f32x4{0.f, 0.f, 0.f, 0.f};
  for (int k0 = 0; k0 < 256; k0 += 32) {
    stage_tile(At, 256, m0, k0, As, tid);
    stage_tile(Bt, 256, n0, k0, Bs, tid);
    __syncthreads();
    bf16x8 a[4], bvv[4];
    #pragma unroll
    for (int i = 0; i < 4; ++i) a[i] = frag(As, wr * 64 + i * 16 + lr, q);
    #pragma unroll
    for (int j = 0; j < 4; ++j) bvv[j] = frag(Bs, wc * 64 + j * 16 + lr, q);
    #pragma unroll
    for (int i = 0; i < 4; ++i)
      #pragma unroll
      for (int j = 0; j < 4; ++j)
        acc[i][j] = __builtin_amdgcn_mfma_f32_16x16x32_bf16(a[i], bvv[j], acc[i][j], 0, 0, 0);
    __syncthreads();
  }
  const int rb = 4 * q;
  #pragma unroll
  for (int i = 0; i < 4; ++i)
    #pragma unroll
    for (int j = 0; j < 4; ++j) {
      const size_t base = (size_t)(m0 + wr * 64 + i * 16 + rb) * 4096 + n0 + wc * 64 + j * 16 + lr;
      #pragma unroll
      for (int r = 0; r < 4; ++r)
        G[base + (size_t)r * 4096] = acc[i][j][r];
    }
}

// ---------------- fused fbuild + softmax -> bf16 P (MLP-optimized) ----------------
// G has >=256 floats of valid guard slack on both sides; invalid rows use a
// clamped dummy pointer, contributions masked via cndmask.
__global__ __launch_bounds__(256) void k_fsoft(const float* __restrict__ G,
    const float* __restrict__ muA, const float* __restrict__ invA,
    const float* __restrict__ muB, const float* __restrict__ invB,
    unsigned short* __restrict__ P) {
  __shared__ float redm[4];
  __shared__ float reds[4];
  // XCD-chunked swizzle: contiguous m-range per XCD -> L2 sliding window
  const int m = ((blockIdx.x & 7) << 9) | (blockIdx.x >> 3);
  const int tid = threadIdx.x;
  const int ym = m >> 6, xm = m & 63;
  const int xn = tid & 63, ty = tid >> 6;

  // block-uniform group setup
  const float* base[9];
  bool xok[9];
  #pragma unroll
  for (int dy = -1; dy <= 1; ++dy) {
    #pragma unroll
    for (int dx = -1; dx <= 1; ++dx) {
      const int g = (dy + 1) * 3 + (dx + 1);
      const bool rv = ((unsigned)(ym + dy) < 64u) && ((unsigned)(xm + dx) < 64u);
      const int d = dy * 64 + dx;
      base[g] = rv ? (G + (size_t)(m + d) * 4096 + d) : G;
      xok[g] = rv && ((unsigned)(xn + dx) < 64u);
    }
  }

  float acc[16];
  #pragma unroll
  for (int u = 0; u < 16; ++u) acc[u] = 0.f;

  #pragma unroll
  for (int uc = 0; uc < 4; ++uc) {
    float v[36];
    #pragma unroll
    for (int g = 0; g < 9; ++g) {
      #pragma unroll
      for (int r = 0; r < 4; ++r) {
        const int u = uc * 4 + r;
        v[g * 4 + r] = base[g][u * 256 + tid];
      }
    }
    #pragma unroll
    for (int g = 0; g < 9; ++g) {
      const int dy = g / 3 - 1;
      #pragma unroll
      for (int r = 0; r < 4; ++r) {
        const int u = uc * 4 + r;
        // yn = 4u + ty; mask folds to constant-true for most u
        const bool ok = xok[g] && ((unsigned)(4 * u + ty + dy) < 64u);
        acc[u] += ok ? v[g * 4 + r] : 0.f;
      }
    }
  }

  const float s1 = 2304.f * muA[m];
  const float ia100 = invA[m] * 100.f;
  float mx = -3.4e38f;
  #pragma unroll
  for (int u = 0; u < 16; ++u) {
    const int n = tid + u * 256;
    const float lg = (acc[u] - s1 * muB[n]) * (ia100 * invB[n]);
    acc[u] = lg;
    mx = fmaxf(mx, lg);
  }
  #pragma unroll
  for (int off = 32; off; off >>= 1) mx = fmaxf(mx, __shfl_xor(mx, off));
  const int wave = tid >> 6, lane = tid & 63;
  if (lane == 0) redm[wave] = mx;
  __syncthreads();
  mx = fmaxf(fmaxf(redm[0], redm[1]), fmaxf(redm[2], redm[3]));
  float s = 0.f;
  #pragma unroll
  for (int u = 0; u < 16; ++u) {
    acc[u] = __expf(acc[u] - mx);
    s += acc[u];
  }
  #pragma unroll
  for (int off = 32; off; off >>= 1) s += __shfl_xor(s, off);
  if (lane == 0) reds[wave] = s;
  __syncthreads();
  s = reds[0] + reds[1] + reds[2] + reds[3];
  const float inv = 1.f / s;
  unsigned short* row = P + (size_t)m * 4096;
  #pragma unroll
  for (int u = 0; u < 16; ++u)
    row[tid + u * 256] = f2bf(acc[u] * inv);
}

// ---------------- Y += CF^T x P^T : split-K ----------------
__global__ __launch_bounds__(256) void k_pv(const unsigned short* __restrict__ CFt,
    const unsigned short* __restrict__ P, float* __restrict__ Y) {
  __shared__ unsigned short As[128 * ROWP];
  __shared__ unsigned short Bs[128 * ROWP];
  const int tid = threadIdx.x;
  const int c0 = blockIdx.y * 128, mb0 = blockIdx.x * 128;
  const int kbase = blockIdx.z * 512;
  const int l = tid & 63, w = tid >> 6;
  const int wr = w >> 1, wc = w & 1;
  const int q = l >> 4, lr = l & 15;
  f32x4 acc[4][4];
  #pragma unroll
  for (int i = 0; i < 4; ++i)
    #pragma unroll
    for (int j = 0; j < 4; ++j)
      acc[i][j] = f32x4{0.f, 0.f, 0.f, 0.f};
  for (int ks = 0; ks < 512; ks += 32) {
    const int k0 = kbase + ks;
    stage_tile(CFt, 4096, c0, k0, As, tid);
    stage_tile(P, 4096, mb0, k0, Bs, tid);
    __syncthreads();
    bf16x8 a[4], bvv[4];
    #pragma unroll
    for (int i = 0; i < 4; ++i) a[i] = frag(As, wr * 64 + i * 16 + lr, q);
    #pragma unroll
    for (int j = 0; j < 4; ++j) bvv[j] = frag(Bs, wc * 64 + j * 16 + lr, q);
    #pragma unroll
    for (int i = 0; i < 4; ++i)
      #pragma unroll
      for (int j = 0; j < 4; ++j)
        acc[i][j] = __builtin_amdgcn_mfma_f32_16x16x32_bf16(a[i], bvv[j], acc[i][j], 0, 0, 0);
    __syncthreads();
  }
  const int rb = 4 * q;
  #pragma unroll
  for (int i = 0; i < 4; ++i)
    #pragma unroll
    for (int j = 0; j < 4; ++j) {
      #pragma unroll
      for (int r = 0; r < 4; ++r) {
        const size_t o = (size_t)(c0 + wr * 64 + i * 16 + rb + r) * 4096 + mb0 + wc * 64 + j * 16 + lr;
        atomicAdd(&Y[o], acc[i][j][r]);
      }
    }
}

// ---------------- final conv ----------------
__global__ __launch_bounds__(256) void k_final(const float* __restrict__ WC,
    const float* __restrict__ bc, const float* __restrict__ BF,
    const float* __restrict__ Y, float* __restrict__ OUT) {
  __shared__ float As[16][68];
  __shared__ float Bs[16][64];
  const int b = blockIdx.z;
  const int tid = threadIdx.x;
  const int tx = tid & 15, ty = tid >> 4;
  const int o0 = blockIdx.y * 64, m0 = blockIdx.x * 64;
  float acc[4][4] = {};
  for (int k0 = 0; k0 < 512; k0 += 16) {
    #pragma unroll
    for (int t = 0; t < 4; ++t) {
      const int e = tid + t * 256;
      const int oo = e >> 4, kk = e & 15;
      As[kk][oo] = WC[(size_t)(o0 + oo) * 512 + k0 + kk];
    }
    #pragma unroll
    for (int t = 0; t < 4; ++t) {
      const int e = tid + t * 256;
      const int kk = e >> 6, col = e & 63;
      const int k = k0 + kk;
      const float* src = (k < 256)
          ? (BF + ((size_t)(b * 256 + k)) * 4096)
          : (Y + ((size_t)(b * 256 + (k - 256))) * 4096);
      Bs[kk][col] = src[m0 + col];
    }
    __syncthreads();
    #pragma unroll
    for (int k = 0; k < 16; ++k) {
      const float4 a4 = *reinterpret_cast<const float4*>(&As[k][ty * 4]);
      const float4 b4 = *reinterpret_cast<const float4*>(&Bs[k][tx * 4]);
      const float av[4] = {a4.x, a4.y, a4.z, a4.w};
      const float bv[4] = {b4.x, b4.y, b4.z, b4.w};
      #pragma unroll
      for (int i = 0; i < 4; ++i)
        #pragma unroll
        for (int j = 0; j < 4; ++j)
          acc[i][j] += av[i] * bv[j];
    }
    __syncthreads();
  }
  #pragma unroll
  for (int i = 0; i < 4; ++i) {
    const int o = o0 + ty * 4 + i;
    const float bias = bc[o];
    float4 v = make_float4(acc[i][0] + bias, acc[i][1] + bias,
                           acc[i][2] + bias, acc[i][3] + bias);
    *reinterpret_cast<float4*>(&OUT[((size_t)(b * 256 + o)) * 4096 + m0 + tx * 4]) = v;
  }
}

extern "C" void kernel_launch(void* const* d_in, const int* in_sizes, int n_in,
                              void* d_out, int out_size, void* d_ws, size_t ws_size,
                              hipStream_t stream) {
  const float* block_fea = (const float*)d_in[0];
  const float* spp       = (const float*)d_in[1];
  const float* click     = (const float*)d_in[2];
  const float* w1 = (const float*)d_in[3];
  const float* b1 = (const float*)d_in[4];
  const float* w2 = (const float*)d_in[5];
  const float* b2 = (const float*)d_in[6];
  const float* w3 = (const float*)d_in[7];
  const float* b3 = (const float*)d_in[8];
  const float* wc = (const float*)d_in[9];
  const float* bc = (const float*)d_in[10];
  float* out = (float*)d_out;

  float* ws = (float*)d_ws;
  const size_t M1 = 1024 * 1024;
  float* cf2  = ws;                         // 8M f (dead before G written)
  float* G    = ws + 256;                   // 16M f, 256-float guards both sides
  unsigned short* Pb  = (unsigned short*)(ws + 17 * M1);   // 16M ushort
  unsigned short* At  = (unsigned short*)(ws + 25 * M1);   // 4M ushort
  unsigned short* Bt  = (unsigned short*)(ws + 27 * M1);   // 4M ushort
  unsigned short* CFt = (unsigned short*)(ws + 29 * M1);   // 4M ushort
  float* cf3  = ws + 31 * M1;               // 4M f
  float* Y    = ws + 35 * M1;               // 4M f
  float* SA   = ws + 39 * M1;               // stats contiguous after Y region
  float* QA   = SA + 16384;
  float* SB   = QA + 16384;
  float* QB   = SB + 16384;
  float* muA  = QB + 16384;
  float* invA = muA + 16384;
  float* muB  = invA + 16384;
  float* invB = muB + 16384;

  // zero Y (4M) + SA..QB (64K) : 4,259,840 floats = 4160 blocks x 1024
  k_zero<<<dim3(4160), 256, 0, stream>>>(Y);
  k_pyr1<<<dim3(1024, 4), 128, 0, stream>>>(click, w1, b1, w2, b2, cf2);
  k_pyr2<<<dim3(256, 4), 256, 0, stream>>>(cf2, w3, b3, cf3);
  k_tcast<<<dim3(64, 4, 4), 256, 0, stream>>>(block_fea, At, 256, 4096,
                                              (size_t)256 * 4096, (size_t)4096 * 256, SA, QA);
  k_tcast<<<dim3(64, 4, 4), 256, 0, stream>>>(spp, Bt, 256, 4096,
                                              (size_t)256 * 4096, (size_t)4096 * 256, SB, QB);
  k_tcast<<<dim3(4, 64, 4), 256, 0, stream>>>(cf3, CFt, 4096, 256,
                                              (size_t)4096 * 256, (size_t)256 * 4096,
                                              (float*)nullptr, (float*)nullptr);
  k_stats9<<<dim3(16, 4), 256, 0, stream>>>(SA, QA, SB, QB, muA, invA, muB, invB);

  for (int b = 0; b < 4; ++b) {
    const unsigned short* Atb = At + (size_t)b * 4096 * 256;
    const unsigned short* Btb = Bt + (size_t)b * 4096 * 256;
    k_gemm_g<<<dim3(32, 32), 256, 0, stream>>>(Atb, Btb, G);
    k_fsoft<<<dim3(4096), 256, 0, stream>>>(G, muA + b * 4096, invA + b * 4096,
                                            muB + b * 4096, invB + b * 4096, Pb);
    k_pv<<<dim3(32, 2, 8), 256, 0, stream>>>(CFt + (size_t)b * 256 * 4096, Pb,
                                             Y + (size_t)b * 256 * 4096);
  }

  k_final<<<dim3(64, 4, 4), 256, 0, stream>>>(wc, bc, block_fea, Y, out);
}

// Round 9
// 574.776 us; speedup vs baseline: 4.3544x; 1.0876x over previous
//
#include <hip/hip_runtime.h>
#include <math.h>

#define EPSF 2.220446049250313e-16f

typedef short bf16x8 __attribute__((ext_vector_type(8)));
typedef float f32x4 __attribute__((ext_vector_type(4)));

static __device__ __forceinline__ unsigned short f2bf(float x) {
  union { float f; unsigned u; } v; v.f = x;
  unsigned r = v.u + 0x7fffu + ((v.u >> 16) & 1u);
  return (unsigned short)(r >> 16);
}

// ---------------- grid-stride zero (stats arrays) ----------------
__global__ __launch_bounds__(256) void k_zero(float* __restrict__ p) {
  const int t = blockIdx.x * 256 + threadIdx.x;
  float4 z = make_float4(0.f, 0.f, 0.f, 0.f);
  *reinterpret_cast<float4*>(&p[(size_t)t * 4]) = z;
}

// ---------------- split + cast wc into wcL/wcR bf16 [256][256] ----------------
__global__ __launch_bounds__(256) void k_wsplit(const float* __restrict__ wc,
    unsigned short* __restrict__ wcLb, unsigned short* __restrict__ wcRb) {
  const int idx = blockIdx.x * 256 + threadIdx.x;   // 0..131071
  const int o = idx >> 9, k = idx & 511;
  const float v = wc[idx];
  if (k < 256) wcLb[o * 256 + k] = f2bf(v);
  else         wcRb[o * 256 + (k - 256)] = f2bf(v);
}

// ---------------- transpose + cast to bf16 (+ optional col stats) ----------------
__global__ __launch_bounds__(256) void k_tcast(const float* __restrict__ src0,
    unsigned short* __restrict__ dst0, int R, int C,
    size_t src_z, size_t dst_z, float* __restrict__ SA, float* __restrict__ QA) {
  __shared__ float ld[64][65];
  const float* src = src0 + blockIdx.z * src_z;
  unsigned short* dst = dst0 + blockIdx.z * dst_z;
  const int c0 = blockIdx.x * 64, r0 = blockIdx.y * 64;
  const int t = threadIdx.x;
  const int colr = t & 63, rowr = t >> 6;
  float s = 0.f, q = 0.f;
  #pragma unroll
  for (int i = 0; i < 16; ++i) {
    const int rl = rowr + i * 4;
    const float v = src[(size_t)(r0 + rl) * C + c0 + colr];
    ld[colr][rl] = v;
    s += v; q += v * v;
  }
  if (SA) {
    atomicAdd(&SA[blockIdx.z * 4096 + c0 + colr], s);
    atomicAdd(&QA[blockIdx.z * 4096 + c0 + colr], q);
  }
  __syncthreads();
  const int rl = t & 63, clb = t >> 6;
  #pragma unroll
  for (int i = 0; i < 16; ++i) {
    const int cl = clb + i * 4;
    dst[(size_t)(c0 + cl) * R + r0 + rl] = f2bf(ld[cl][rl]);
  }
}

// ---------------- click pyramid ----------------
__global__ __launch_bounds__(128) void k_pyr1(const float* __restrict__ click,
    const float* __restrict__ w1, const float* __restrict__ b1,
    const float* __restrict__ w2, const float* __restrict__ b2,
    float* __restrict__ cf2) {
  __shared__ float pool1[16][8];
  __shared__ float pooled64[16][64];
  const int b = blockIdx.y;
  const int pg = blockIdx.x;
  const int tid = threadIdx.x;
  {
    const int q = tid >> 3, s = (tid >> 1) & 3, c = tid & 1;
    const int p2 = pg * 16 + q;
    const int y2 = p2 >> 7, x2 = p2 & 127;
    const int sy = s >> 1, sx = s & 1;
    const int row = 4 * y2 + 2 * sy, col = 4 * x2 + 2 * sx;
    const float* base = click + (((size_t)(b * 2 + c)) * 512 + row) * 512 + col;
    pool1[q][s * 2 + c] = fmaxf(fmaxf(base[0], base[1]), fmaxf(base[512], base[513]));
  }
  __syncthreads();
  {
    const int c1 = tid & 63, qh = tid >> 6;
    const float wa = w1[c1 * 2], wb = w1[c1 * 2 + 1], bb = b1[c1];
    #pragma unroll
    for (int r = 0; r < 8; ++r) {
      const int q = qh * 8 + r;
      float v = -3.4e38f;
      #pragma unroll
      for (int s = 0; s < 4; ++s)
        v = fmaxf(v, bb + wa * pool1[q][s * 2] + wb * pool1[q][s * 2 + 1]);
      pooled64[q][c1] = v;
    }
  }
  __syncthreads();
  float acc[16];
  #pragma unroll
  for (int q = 0; q < 16; ++q) acc[q] = b2[tid];
  const float4* wrow = reinterpret_cast<const float4*>(w2 + tid * 64);
  #pragma unroll
  for (int k4 = 0; k4 < 16; ++k4) {
    const float4 w = wrow[k4];
    #pragma unroll
    for (int q = 0; q < 16; ++q) {
      const float4 p = *reinterpret_cast<const float4*>(&pooled64[q][k4 * 4]);
      acc[q] += w.x * p.x + w.y * p.y + w.z * p.z + w.w * p.w;
    }
  }
  #pragma unroll
  for (int q = 0; q < 16; ++q)
    cf2[((size_t)b * 16384 + pg * 16 + q) * 128 + tid] = acc[q];
}

// cf3 emitted directly as bf16, position-major [B][4096 n][256 c]
__global__ __launch_bounds__(256) void k_pyr2(const float* __restrict__ cf2,
    const float* __restrict__ w3, const float* __restrict__ b3,
    unsigned short* __restrict__ cf3b) {
  __shared__ float pooled[16][128];
  const int b = blockIdx.y;
  const int pb = blockIdx.x;
  const int tid = threadIdx.x;
  #pragma unroll
  for (int i = 0; i < 8; ++i) {
    const int idx = tid + 256 * i;
    const int q = idx >> 7, c = idx & 127;
    const int p = pb * 16 + q;
    const int y = p >> 6, x = p & 63;
    const size_t r0 = (size_t)b * 16384 + (2 * y) * 128 + 2 * x;
    const float* s0 = cf2 + r0 * 128 + c;
    pooled[q][c] = fmaxf(fmaxf(s0[0], s0[128]), fmaxf(s0[128 * 128], s0[128 * 129]));
  }
  __syncthreads();
  float acc[16];
  #pragma unroll
  for (int q = 0; q < 16; ++q) acc[q] = b3[tid];
  const float4* wrow = reinterpret_cast<const float4*>(w3 + tid * 128);
  #pragma unroll
  for (int k4 = 0; k4 < 32; ++k4) {
    const float4 w = wrow[k4];
    #pragma unroll
    for (int q = 0; q < 16; ++q) {
      const float4 p = *reinterpret_cast<const float4*>(&pooled[q][k4 * 4]);
      acc[q] += w.x * p.x + w.y * p.y + w.z * p.z + w.w * p.w;
    }
  }
  #pragma unroll
  for (int q = 0; q < 16; ++q)
    cf3b[((size_t)b * 4096 + pb * 16 + q) * 256 + tid] = f2bf(acc[q]);
}

// ---------------- 9-neighborhood stats ----------------
__global__ __launch_bounds__(256) void k_stats9(const float* __restrict__ SA,
    const float* __restrict__ QA, const float* __restrict__ SB, const float* __restrict__ QB,
    float* __restrict__ muA, float* __restrict__ invA,
    float* __restrict__ muB, float* __restrict__ invB) {
  const int b = blockIdx.y;
  const int m = blockIdx.x * 256 + threadIdx.x;
  const int y = m >> 6, x = m & 63;
  const int base = b * 4096;
  float sa = 0, qa = 0, sb = 0, qb = 0;
  #pragma unroll
  for (int dy = -1; dy <= 1; ++dy) {
    const int yy = y + dy;
    if ((unsigned)yy >= 64u) continue;
    #pragma unroll
    for (int dx = -1; dx <= 1; ++dx) {
      const int xx = x + dx;
      if ((unsigned)xx >= 64u) continue;
      const int idx = base + yy * 64 + xx;
      sa += SA[idx]; qa += QA[idx];
      sb += SB[idx]; qb += QB[idx];
    }
  }
  const float ma = sa * (1.f / 2304.f);
  const float mb = sb * (1.f / 2304.f);
  const float na = sqrtf(fmaxf(qa - 2304.f * ma * ma, 0.f));
  const float nb = sqrtf(fmaxf(qb - 2304.f * mb * mb, 0.f));
  muA[base + m] = ma;
  invA[base + m] = 1.f / (na + EPSF);
  muB[base + m] = mb;
  invB[base + m] = 1.f / (nb + EPSF);
}

// ---------------- MFMA tile helpers ----------------
#define ROWP 40
static __device__ __forceinline__ void stage_tile(const unsigned short* __restrict__ src,
    size_t srow, int r0, int k0, unsigned short* __restrict__ lds, int tid) {
  #pragma unroll
  for (int p = 0; p < 2; ++p) {
    const int idx = tid + p * 256;
    const int m = idx >> 2, q = idx & 3;
    const bf16x8 v = *reinterpret_cast<const bf16x8*>(src + (size_t)(r0 + m) * srow + k0 + q * 8);
    *reinterpret_cast<bf16x8*>(lds + m * ROWP + q * 8) = v;
  }
}

static __device__ __forceinline__ bf16x8 frag(const unsigned short* __restrict__ lds,
                                              int row, int q) {
  return *reinterpret_cast<const bf16x8*>(lds + row * ROWP + q * 8);
}

// ---------------- G = A^T B (per batch), bf16 MFMA ----------------
__global__ __launch_bounds__(256) void k_gemm_g(const unsigned short* __restrict__ At,
    const unsigned short* __restrict__ Bt, float* __restrict__ G) {
  __shared__ unsigned short As[128 * ROWP];
  __shared__ unsigned short Bs[128 * ROWP];
  const int tid = threadIdx.x;
  const int lin = blockIdx.y * 32 + blockIdx.x;
  const int nlin = ((lin & 7) << 7) | (lin >> 3);
  const int m0 = (nlin >> 5) * 128, n0 = (nlin & 31) * 128;
  const int l = tid & 63, w = tid >> 6;
  const int wr = w >> 1, wc = w & 1;
  const int q = l >> 4, lr = l & 15;
  f32x4 acc[4][4];
  #pragma unroll
  for (int i = 0; i < 4; ++i)
    #pragma unroll
    for (int j = 0; j < 4; ++j)
      acc[i][j] = f32x4{0.f, 0.f, 0.f, 0.f};
  for (int k0 = 0; k0 < 256; k0 += 32) {
    stage_tile(At, 256, m0, k0, As, tid);
    stage_tile(Bt, 256, n0, k0, Bs, tid);
    __syncthreads();
    bf16x8 a[4], bvv[4];
    #pragma unroll
    for (int i = 0; i < 4; ++i) a[i] = frag(As, wr * 64 + i * 16 + lr, q);
    #pragma unroll
    for (int j = 0; j < 4; ++j) bvv[j] = frag(Bs, wc * 64 + j * 16 + lr, q);
    #pragma unroll
    for (int i = 0; i < 4; ++i)
      #pragma unroll
      for (int j = 0; j < 4; ++j)
        acc[i][j] = __builtin_amdgcn_mfma_f32_16x16x32_bf16(a[i], bvv[j], acc[i][j], 0, 0, 0);
    __syncthreads();
  }
  const int rb = 4 * q;
  #pragma unroll
  for (int i = 0; i < 4; ++i)
    #pragma unroll
    for (int j = 0; j < 4; ++j) {
      const size_t base = (size_t)(m0 + wr * 64 + i * 16 + rb) * 4096 + n0 + wc * 64 + j * 16 + lr;
      #pragma unroll
      for (int r = 0; r < 4; ++r)
        G[base + (size_t)r * 4096] = acc[i][j][r];
    }
}

// ---------------- CF2 = wcR @ CF : bf16 out [256 o][4096 n] per batch ----------------
__global__ __launch_bounds__(256) void k_gemm_cf2(const unsigned short* __restrict__ wcRb,
    const unsigned short* __restrict__ cf3b, unsigned short* __restrict__ CF2t) {
  __shared__ unsigned short As[128 * ROWP];
  __shared__ unsigned short Bs[128 * ROWP];
  const int b = blockIdx.z;
  const int tid = threadIdx.x;
  const int o0 = blockIdx.y * 128, n0 = blockIdx.x * 128;
  const unsigned short* Bb = cf3b + (size_t)b * 4096 * 256;
  unsigned short* outb = CF2t + (size_t)b * 256 * 4096;
  const int l = tid & 63, w = tid >> 6;
  const int wr = w >> 1, wcol = w & 1;
  const int q = l >> 4, lr = l & 15;
  f32x4 acc[4][4];
  #pragma unroll
  for (int i = 0; i < 4; ++i)
    #pragma unroll
    for (int j = 0; j < 4; ++j)
      acc[i][j] = f32x4{0.f, 0.f, 0.f, 0.f};
  for (int k0 = 0; k0 < 256; k0 += 32) {
    stage_tile(wcRb, 256, o0, k0, As, tid);
    stage_tile(Bb, 256, n0, k0, Bs, tid);
    __syncthreads();
    bf16x8 a[4], bvv[4];
    #pragma unroll
    for (int i = 0; i < 4; ++i) a[i] = frag(As, wr * 64 + i * 16 + lr, q);
    #pragma unroll
    for (int j = 0; j < 4; ++j) bvv[j] = frag(Bs, wcol * 64 + j * 16 + lr, q);
    #pragma unroll
    for (int i = 0; i < 4; ++i)
      #pragma unroll
      for (int j = 0; j < 4; ++j)
        acc[i][j] = __builtin_amdgcn_mfma_f32_16x16x32_bf16(a[i], bvv[j], acc[i][j], 0, 0, 0);
    __syncthreads();
  }
  const int rb = 4 * q;
  #pragma unroll
  for (int i = 0; i < 4; ++i)
    #pragma unroll
    for (int j = 0; j < 4; ++j) {
      const size_t base = (size_t)(o0 + wr * 64 + i * 16 + rb) * 4096 + n0 + wcol * 64 + j * 16 + lr;
      #pragma unroll
      for (int r = 0; r < 4; ++r)
        outb[base + (size_t)r * 4096] = f2bf(acc[i][j][r]);
    }
}

// ---------------- OUT init = bc + wcL @ BF : f32 out [b][256 o][4096 m] ----------------
__global__ __launch_bounds__(256) void k_gemm_oinit(const unsigned short* __restrict__ wcLb,
    const unsigned short* __restrict__ At, const float* __restrict__ bc,
    float* __restrict__ OUT) {
  __shared__ unsigned short As[128 * ROWP];
  __shared__ unsigned short Bs[128 * ROWP];
  const int b = blockIdx.z;
  const int tid = threadIdx.x;
  const int o0 = blockIdx.y * 128, m0 = blockIdx.x * 128;
  const unsigned short* Bb = At + (size_t)b * 4096 * 256;
  float* outb = OUT + (size_t)b * 256 * 4096;
  const int l = tid & 63, w = tid >> 6;
  const int wr = w >> 1, wcol = w & 1;
  const int q = l >> 4, lr = l & 15;
  f32x4 acc[4][4];
  #pragma unroll
  for (int i = 0; i < 4; ++i)
    #pragma unroll
    for (int j = 0; j < 4; ++j)
      acc[i][j] = f32x4{0.f, 0.f, 0.f, 0.f};
  for (int k0 = 0; k0 < 256; k0 += 32) {
    stage_tile(wcLb, 256, o0, k0, As, tid);
    stage_tile(Bb, 256, m0, k0, Bs, tid);
    __syncthreads();
    bf16x8 a[4], bvv[4];
    #pragma unroll
    for (int i = 0; i < 4; ++i) a[i] = frag(As, wr * 64 + i * 16 + lr, q);
    #pragma unroll
    for (int j = 0; j < 4; ++j) bvv[j] = frag(Bs, wcol * 64 + j * 16 + lr, q);
    #pragma unroll
    for (int i = 0; i < 4; ++i)
      #pragma unroll
      for (int j = 0; j < 4; ++j)
        acc[i][j] = __builtin_amdgcn_mfma_f32_16x16x32_bf16(a[i], bvv[j], acc[i][j], 0, 0, 0);
    __syncthreads();
  }
  const int rb = 4 * q;
  #pragma unroll
  for (int i = 0; i < 4; ++i)
    #pragma unroll
    for (int j = 0; j < 4; ++j) {
      #pragma unroll
      for (int r = 0; r < 4; ++r) {
        const int o = o0 + wr * 64 + i * 16 + rb + r;
        outb[(size_t)o * 4096 + m0 + wcol * 64 + j * 16 + lr] = acc[i][j][r] + bc[o];
      }
    }
}

// ---------------- fused fbuild + softmax -> bf16 P ----------------
__global__ __launch_bounds__(256) void k_fsoft(const float* __restrict__ G,
    const float* __restrict__ muA, const float* __restrict__ invA,
    const float* __restrict__ muB, const float* __restrict__ invB,
    unsigned short* __restrict__ P) {
  __shared__ float redm[4];
  __shared__ float reds[4];
  const int m = ((blockIdx.x & 7) << 9) | (blockIdx.x >> 3);
  const int tid = threadIdx.x;
  const int ym = m >> 6, xm = m & 63;
  const int xn = tid & 63, ty = tid >> 6;

  const float* base[9];
  bool xok[9];
  #pragma unroll
  for (int dy = -1; dy <= 1; ++dy) {
    #pragma unroll
    for (int dx = -1; dx <= 1; ++dx) {
      const int g = (dy + 1) * 3 + (dx + 1);
      const bool rv = ((unsigned)(ym + dy) < 64u) && ((unsigned)(xm + dx) < 64u);
      const int d = dy * 64 + dx;
      base[g] = rv ? (G + (size_t)(m + d) * 4096 + d) : G;
      xok[g] = rv && ((unsigned)(xn + dx) < 64u);
    }
  }

  float acc[16];
  #pragma unroll
  for (int u = 0; u < 16; ++u) acc[u] = 0.f;

  #pragma unroll
  for (int uc = 0; uc < 4; ++uc) {
    float v[36];
    #pragma unroll
    for (int g = 0; g < 9; ++g) {
      #pragma unroll
      for (int r = 0; r < 4; ++r) {
        const int u = uc * 4 + r;
        v[g * 4 + r] = base[g][u * 256 + tid];
      }
    }
    #pragma unroll
    for (int g = 0; g < 9; ++g) {
      const int dy = g / 3 - 1;
      #pragma unroll
      for (int r = 0; r < 4; ++r) {
        const int u = uc * 4 + r;
        const bool ok = xok[g] && ((unsigned)(4 * u + ty + dy) < 64u);
        acc[u] += ok ? v[g * 4 + r] : 0.f;
      }
    }
  }

  const float s1 = 2304.f * muA[m];
  const float ia100 = invA[m] * 100.f;
  float mx = -3.4e38f;
  #pragma unroll
  for (int u = 0; u < 16; ++u) {
    const int n = tid + u * 256;
    const float lg = (acc[u] - s1 * muB[n]) * (ia100 * invB[n]);
    acc[u] = lg;
    mx = fmaxf(mx, lg);
  }
  #pragma unroll
  for (int off = 32; off; off >>= 1) mx = fmaxf(mx, __shfl_xor(mx, off));
  const int wave = tid >> 6, lane = tid & 63;
  if (lane == 0) redm[wave] = mx;
  __syncthreads();
  mx = fmaxf(fmaxf(redm[0], redm[1]), fmaxf(redm[2], redm[3]));
  float s = 0.f;
  #pragma unroll
  for (int u = 0; u < 16; ++u) {
    acc[u] = __expf(acc[u] - mx);
    s += acc[u];
  }
  #pragma unroll
  for (int off = 32; off; off >>= 1) s += __shfl_xor(s, off);
  if (lane == 0) reds[wave] = s;
  __syncthreads();
  s = reds[0] + reds[1] + reds[2] + reds[3];
  const float inv = 1.f / s;
  unsigned short* row = P + (size_t)m * 4096;
  #pragma unroll
  for (int u = 0; u < 16; ++u)
    row[tid + u * 256] = f2bf(acc[u] * inv);
}

// ---------------- OUT += CF2 x P^T : split-K, atomics into d_out ----------------
__global__ __launch_bounds__(256) void k_pv(const unsigned short* __restrict__ CF2t,
    const unsigned short* __restrict__ P, float* __restrict__ OUT) {
  __shared__ unsigned short As[128 * ROWP];
  __shared__ unsigned short Bs[128 * ROWP];
  const int tid = threadIdx.x;
  const int c0 = blockIdx.y * 128, mb0 = blockIdx.x * 128;
  const int kbase = blockIdx.z * 512;
  const int l = tid & 63, w = tid >> 6;
  const int wr = w >> 1, wc = w & 1;
  const int q = l >> 4, lr = l & 15;
  f32x4 acc[4][4];
  #pragma unroll
  for (int i = 0; i < 4; ++i)
    #pragma unroll
    for (int j = 0; j < 4; ++j)
      acc[i][j] = f32x4{0.f, 0.f, 0.f, 0.f};
  for (int ks = 0; ks < 512; ks += 32) {
    const int k0 = kbase + ks;
    stage_tile(CF2t, 4096, c0, k0, As, tid);
    stage_tile(P, 4096, mb0, k0, Bs, tid);
    __syncthreads();
    bf16x8 a[4], bvv[4];
    #pragma unroll
    for (int i = 0; i < 4; ++i) a[i] = frag(As, wr * 64 + i * 16 + lr, q);
    #pragma unroll
    for (int j = 0; j < 4; ++j) bvv[j] = frag(Bs, wc * 64 + j * 16 + lr, q);
    #pragma unroll
    for (int i = 0; i < 4; ++i)
      #pragma unroll
      for (int j = 0; j < 4; ++j)
        acc[i][j] = __builtin_amdgcn_mfma_f32_16x16x32_bf16(a[i], bvv[j], acc[i][j], 0, 0, 0);
    __syncthreads();
  }
  const int rb = 4 * q;
  #pragma unroll
  for (int i = 0; i < 4; ++i)
    #pragma unroll
    for (int j = 0; j < 4; ++j) {
      #pragma unroll
      for (int r = 0; r < 4; ++r) {
        const size_t o = (size_t)(c0 + wr * 64 + i * 16 + rb + r) * 4096 + mb0 + wc * 64 + j * 16 + lr;
        atomicAdd(&OUT[o], acc[i][j][r]);
      }
    }
}

extern "C" void kernel_launch(void* const* d_in, const int* in_sizes, int n_in,
                              void* d_out, int out_size, void* d_ws, size_t ws_size,
                              hipStream_t stream) {
  const float* block_fea = (const float*)d_in[0];
  const float* spp       = (const float*)d_in[1];
  const float* click     = (const float*)d_in[2];
  const float* w1 = (const float*)d_in[3];
  const float* b1 = (const float*)d_in[4];
  const float* w2 = (const float*)d_in[5];
  const float* b2 = (const float*)d_in[6];
  const float* w3 = (const float*)d_in[7];
  const float* b3 = (const float*)d_in[8];
  const float* wc = (const float*)d_in[9];
  const float* bc = (const float*)d_in[10];
  float* out = (float*)d_out;

  float* ws = (float*)d_ws;
  const size_t M1 = 1024 * 1024;
  float* cf2  = ws;                          // 8M f (dead before G written)
  float* G    = ws + 256;                    // 16M f, guard slack both sides
  unsigned short* Pb   = (unsigned short*)(ws + 17 * M1);  // 16M ushort
  unsigned short* At   = (unsigned short*)(ws + 25 * M1);  // 4M ushort
  unsigned short* Bt   = (unsigned short*)(ws + 27 * M1);  // 4M ushort
  unsigned short* CF3b = (unsigned short*)(ws + 29 * M1);  // 4M ushort
  unsigned short* CF2t = (unsigned short*)(ws + 31 * M1);  // 8M ushort
  unsigned short* wcLb = (unsigned short*)(ws + 35 * M1);  // 64K ushort
  unsigned short* wcRb = wcLb + 65536;                     // 64K ushort
  float* SA   = ws + 36 * M1;
  float* QA   = SA + 16384;
  float* SB   = QA + 16384;
  float* QB   = SB + 16384;
  float* muA  = QB + 16384;
  float* invA = muA + 16384;
  float* muB  = invA + 16384;
  float* invB = muB + 16384;

  // zero stats (SA..QB = 65536 floats)
  k_zero<<<dim3(64), 256, 0, stream>>>(SA);
  k_wsplit<<<dim3(512), 256, 0, stream>>>(wc, wcLb, wcRb);
  k_pyr1<<<dim3(1024, 4), 128, 0, stream>>>(click, w1, b1, w2, b2, cf2);
  k_pyr2<<<dim3(256, 4), 256, 0, stream>>>(cf2, w3, b3, CF3b);
  k_tcast<<<dim3(64, 4, 4), 256, 0, stream>>>(block_fea, At, 256, 4096,
                                              (size_t)256 * 4096, (size_t)4096 * 256, SA, QA);
  k_tcast<<<dim3(64, 4, 4), 256, 0, stream>>>(spp, Bt, 256, 4096,
                                              (size_t)256 * 4096, (size_t)4096 * 256, SB, QB);
  k_stats9<<<dim3(16, 4), 256, 0, stream>>>(SA, QA, SB, QB, muA, invA, muB, invB);
  k_gemm_cf2<<<dim3(32, 2, 4), 256, 0, stream>>>(wcRb, CF3b, CF2t);
  k_gemm_oinit<<<dim3(32, 2, 4), 256, 0, stream>>>(wcLb, At, bc, out);

  for (int b = 0; b < 4; ++b) {
    const unsigned short* Atb = At + (size_t)b * 4096 * 256;
    const unsigned short* Btb = Bt + (size_t)b * 4096 * 256;
    k_gemm_g<<<dim3(32, 32), 256, 0, stream>>>(Atb, Btb, G);
    k_fsoft<<<dim3(4096), 256, 0, stream>>>(G, muA + b * 4096, invA + b * 4096,
                                            muB + b * 4096, invB + b * 4096, Pb);
    k_pv<<<dim3(32, 2, 8), 256, 0, stream>>>(CF2t + (size_t)b * 256 * 4096, Pb,
                                             out + (size_t)b * 256 * 4096);
  }
}

// Round 12
// 555.446 us; speedup vs baseline: 4.5059x; 1.0348x over previous
//
#include <hip/hip_runtime.h>
#include <math.h>

#define EPSF 2.220446049250313e-16f

typedef short bf16x8 __attribute__((ext_vector_type(8)));
typedef float f32x4 __attribute__((ext_vector_type(4)));

static __device__ __forceinline__ unsigned short f2bf(float x) {
  union { float f; unsigned u; } v; v.f = x;
  unsigned r = v.u + 0x7fffu + ((v.u >> 16) & 1u);
  return (unsigned short)(r >> 16);
}

// ---------------- grid-stride zero (stats arrays) ----------------
__global__ __launch_bounds__(256) void k_zero(float* __restrict__ p) {
  const int t = blockIdx.x * 256 + threadIdx.x;
  float4 z = make_float4(0.f, 0.f, 0.f, 0.f);
  *reinterpret_cast<float4*>(&p[(size_t)t * 4]) = z;
}

// ---------------- split + cast wc into wcL/wcR bf16 [256][256] ----------------
__global__ __launch_bounds__(256) void k_wsplit(const float* __restrict__ wc,
    unsigned short* __restrict__ wcLb, unsigned short* __restrict__ wcRb) {
  const int idx = blockIdx.x * 256 + threadIdx.x;   // 0..131071
  const int o = idx >> 9, k = idx & 511;
  const float v = wc[idx];
  if (k < 256) wcLb[o * 256 + k] = f2bf(v);
  else         wcRb[o * 256 + (k - 256)] = f2bf(v);
}

// ---------------- transpose + cast to bf16 (+ optional col stats) ----------------
__global__ __launch_bounds__(256) void k_tcast(const float* __restrict__ src0,
    unsigned short* __restrict__ dst0, int R, int C,
    size_t src_z, size_t dst_z, float* __restrict__ SA, float* __restrict__ QA) {
  __shared__ float ld[64][65];
  const float* src = src0 + blockIdx.z * src_z;
  unsigned short* dst = dst0 + blockIdx.z * dst_z;
  const int c0 = blockIdx.x * 64, r0 = blockIdx.y * 64;
  const int t = threadIdx.x;
  const int colr = t & 63, rowr = t >> 6;
  float s = 0.f, q = 0.f;
  #pragma unroll
  for (int i = 0; i < 16; ++i) {
    const int rl = rowr + i * 4;
    const float v = src[(size_t)(r0 + rl) * C + c0 + colr];
    ld[colr][rl] = v;
    s += v; q += v * v;
  }
  if (SA) {
    atomicAdd(&SA[blockIdx.z * 4096 + c0 + colr], s);
    atomicAdd(&QA[blockIdx.z * 4096 + c0 + colr], q);
  }
  __syncthreads();
  const int rl = t & 63, clb = t >> 6;
  #pragma unroll
  for (int i = 0; i < 16; ++i) {
    const int cl = clb + i * 4;
    dst[(size_t)(c0 + cl) * R + r0 + rl] = f2bf(ld[cl][rl]);
  }
}

// ---------------- click pyramid ----------------
__global__ __launch_bounds__(128) void k_pyr1(const float* __restrict__ click,
    const float* __restrict__ w1, const float* __restrict__ b1,
    const float* __restrict__ w2, const float* __restrict__ b2,
    float* __restrict__ cf2) {
  __shared__ float pool1[16][8];
  __shared__ float pooled64[16][64];
  const int b = blockIdx.y;
  const int pg = blockIdx.x;
  const int tid = threadIdx.x;
  {
    const int q = tid >> 3, s = (tid >> 1) & 3, c = tid & 1;
    const int p2 = pg * 16 + q;
    const int y2 = p2 >> 7, x2 = p2 & 127;
    const int sy = s >> 1, sx = s & 1;
    const int row = 4 * y2 + 2 * sy, col = 4 * x2 + 2 * sx;
    const float* base = click + (((size_t)(b * 2 + c)) * 512 + row) * 512 + col;
    pool1[q][s * 2 + c] = fmaxf(fmaxf(base[0], base[1]), fmaxf(base[512], base[513]));
  }
  __syncthreads();
  {
    const int c1 = tid & 63, qh = tid >> 6;
    const float wa = w1[c1 * 2], wb = w1[c1 * 2 + 1], bb = b1[c1];
    #pragma unroll
    for (int r = 0; r < 8; ++r) {
      const int q = qh * 8 + r;
      float v = -3.4e38f;
      #pragma unroll
      for (int s = 0; s < 4; ++s)
        v = fmaxf(v, bb + wa * pool1[q][s * 2] + wb * pool1[q][s * 2 + 1]);
      pooled64[q][c1] = v;
    }
  }
  __syncthreads();
  float acc[16];
  #pragma unroll
  for (int q = 0; q < 16; ++q) acc[q] = b2[tid];
  const float4* wrow = reinterpret_cast<const float4*>(w2 + tid * 64);
  #pragma unroll
  for (int k4 = 0; k4 < 16; ++k4) {
    const float4 w = wrow[k4];
    #pragma unroll
    for (int q = 0; q < 16; ++q) {
      const float4 p = *reinterpret_cast<const float4*>(&pooled64[q][k4 * 4]);
      acc[q] += w.x * p.x + w.y * p.y + w.z * p.z + w.w * p.w;
    }
  }
  #pragma unroll
  for (int q = 0; q < 16; ++q)
    cf2[((size_t)b * 16384 + pg * 16 + q) * 128 + tid] = acc[q];
}

// cf3 emitted directly as bf16, position-major [B][4096 n][256 c]
__global__ __launch_bounds__(256) void k_pyr2(const float* __restrict__ cf2,
    const float* __restrict__ w3, const float* __restrict__ b3,
    unsigned short* __restrict__ cf3b) {
  __shared__ float pooled[16][128];
  const int b = blockIdx.y;
  const int pb = blockIdx.x;
  const int tid = threadIdx.x;
  #pragma unroll
  for (int i = 0; i < 8; ++i) {
    const int idx = tid + 256 * i;
    const int q = idx >> 7, c = idx & 127;
    const int p = pb * 16 + q;
    const int y = p >> 6, x = p & 63;
    const size_t r0 = (size_t)b * 16384 + (2 * y) * 128 + 2 * x;
    const float* s0 = cf2 + r0 * 128 + c;
    pooled[q][c] = fmaxf(fmaxf(s0[0], s0[128]), fmaxf(s0[128 * 128], s0[128 * 129]));
  }
  __syncthreads();
  float acc[16];
  #pragma unroll
  for (int q = 0; q < 16; ++q) acc[q] = b3[tid];
  const float4* wrow = reinterpret_cast<const float4*>(w3 + tid * 128);
  #pragma unroll
  for (int k4 = 0; k4 < 32; ++k4) {
    const float4 w = wrow[k4];
    #pragma unroll
    for (int q = 0; q < 16; ++q) {
      const float4 p = *reinterpret_cast<const float4*>(&pooled[q][k4 * 4]);
      acc[q] += w.x * p.x + w.y * p.y + w.z * p.z + w.w * p.w;
    }
  }
  #pragma unroll
  for (int q = 0; q < 16; ++q)
    cf3b[((size_t)b * 4096 + pb * 16 + q) * 256 + tid] = f2bf(acc[q]);
}

// ---------------- 9-neighborhood stats ----------------
__global__ __launch_bounds__(256) void k_stats9(const float* __restrict__ SA,
    const float* __restrict__ QA, const float* __restrict__ SB, const float* __restrict__ QB,
    float* __restrict__ muA, float* __restrict__ invA,
    float* __restrict__ muB, float* __restrict__ invB) {
  const int b = blockIdx.y;
  const int m = blockIdx.x * 256 + threadIdx.x;
  const int y = m >> 6, x = m & 63;
  const int base = b * 4096;
  float sa = 0, qa = 0, sb = 0, qb = 0;
  #pragma unroll
  for (int dy = -1; dy <= 1; ++dy) {
    const int yy = y + dy;
    if ((unsigned)yy >= 64u) continue;
    #pragma unroll
    for (int dx = -1; dx <= 1; ++dx) {
      const int xx = x + dx;
      if ((unsigned)xx >= 64u) continue;
      const int idx = base + yy * 64 + xx;
      sa += SA[idx]; qa += QA[idx];
      sb += SB[idx]; qb += QB[idx];
    }
  }
  const float ma = sa * (1.f / 2304.f);
  const float mb = sb * (1.f / 2304.f);
  const float na = sqrtf(fmaxf(qa - 2304.f * ma * ma, 0.f));
  const float nb = sqrtf(fmaxf(qb - 2304.f * mb * mb, 0.f));
  muA[base + m] = ma;
  invA[base + m] = 1.f / (na + EPSF);
  muB[base + m] = mb;
  invB[base + m] = 1.f / (nb + EPSF);
}

// ---------------- MFMA tile helpers ----------------
#define ROWP 40
static __device__ __forceinline__ bf16x8 frag(const unsigned short* __restrict__ lds,
                                              int row, int q) {
  return *reinterpret_cast<const bf16x8*>(lds + row * ROWP + q * 8);
}
static __device__ __forceinline__ bf16x8 ldg8(const unsigned short* p) {
  return *reinterpret_cast<const bf16x8*>(p);
}

// Double-buffered 128x128 MFMA GEMM inner loop: one barrier per K-step,
// next-tile global loads issued into registers before the current MFMAs
// (latency hidden), ds_writes to the other buffer after.
static __device__ __forceinline__ void mfma_dbuf(
    const unsigned short* __restrict__ Aop, size_t sA, int ra0,
    const unsigned short* __restrict__ Bop, size_t sB, int rb0,
    int k0, int nk,
    unsigned short* As0, unsigned short* As1,
    unsigned short* Bs0, unsigned short* Bs1,
    int tid, f32x4 (&acc)[4][4]) {
  const int l = tid & 63, w = tid >> 6;
  const int wr = w >> 1, wcc = w & 1;
  const int q = l >> 4, lr = l & 15;
  const int rr = tid >> 2, qq = tid & 3;
  const unsigned short* pa0 = Aop + (size_t)(ra0 + rr) * sA + qq * 8 + k0;
  const unsigned short* pa1 = Aop + (size_t)(ra0 + 64 + rr) * sA + qq * 8 + k0;
  const unsigned short* pb0 = Bop + (size_t)(rb0 + rr) * sB + qq * 8 + k0;
  const unsigned short* pb1 = Bop + (size_t)(rb0 + 64 + rr) * sB + qq * 8 + k0;
  const int wo0 = rr * ROWP + qq * 8;
  const int wo1 = (64 + rr) * ROWP + qq * 8;
  // prologue: stage tile 0
  *reinterpret_cast<bf16x8*>(As0 + wo0) = ldg8(pa0);
  *reinterpret_cast<bf16x8*>(As0 + wo1) = ldg8(pa1);
  *reinterpret_cast<bf16x8*>(Bs0 + wo0) = ldg8(pb0);
  *reinterpret_cast<bf16x8*>(Bs0 + wo1) = ldg8(pb1);
  __syncthreads();
  unsigned short *Ac = As0, *An = As1, *Bc = Bs0, *Bn = Bs1;
  for (int t = 0; t < nk; ++t) {
    const bool more = (t + 1) < nk;
    const int kk = (t + 1) * 32;
    bf16x8 na0, na1, nb0, nb1;
    if (more) {
      na0 = ldg8(pa0 + kk);
      na1 = ldg8(pa1 + kk);
      nb0 = ldg8(pb0 + kk);
      nb1 = ldg8(pb1 + kk);
    }
    bf16x8 a[4], bv[4];
    #pragma unroll
    for (int i = 0; i < 4; ++i) a[i] = frag(Ac, wr * 64 + i * 16 + lr, q);
    #pragma unroll
    for (int j = 0; j < 4; ++j) bv[j] = frag(Bc, wcc * 64 + j * 16 + lr, q);
    #pragma unroll
    for (int i = 0; i < 4; ++i)
      #pragma unroll
      for (int j = 0; j < 4; ++j)
        acc[i][j] = __builtin_amdgcn_mfma_f32_16x16x32_bf16(a[i], bv[j], acc[i][j], 0, 0, 0);
    if (more) {
      *reinterpret_cast<bf16x8*>(An + wo0) = na0;
      *reinterpret_cast<bf16x8*>(An + wo1) = na1;
      *reinterpret_cast<bf16x8*>(Bn + wo0) = nb0;
      *reinterpret_cast<bf16x8*>(Bn + wo1) = nb1;
    }
    __syncthreads();
    unsigned short* tp;
    tp = Ac; Ac = An; An = tp;
    tp = Bc; Bc = Bn; Bn = tp;
  }
}

// ---------------- G = A^T B (per batch), bf16 MFMA ----------------
__global__ __launch_bounds__(256) void k_gemm_g(const unsigned short* __restrict__ At,
    const unsigned short* __restrict__ Bt, float* __restrict__ G) {
  __shared__ unsigned short As[2][128 * ROWP];
  __shared__ unsigned short Bs[2][128 * ROWP];
  const int tid = threadIdx.x;
  const int lin = blockIdx.y * 32 + blockIdx.x;
  const int nlin = ((lin & 7) << 7) | (lin >> 3);
  const int m0 = (nlin >> 5) * 128, n0 = (nlin & 31) * 128;
  const int l = tid & 63, w = tid >> 6;
  const int wr = w >> 1, wc = w & 1;
  const int q = l >> 4, lr = l & 15;
  f32x4 acc[4][4];
  #pragma unroll
  for (int i = 0; i < 4; ++i)
    #pragma unroll
    for (int j = 0; j < 4; ++j)
      acc[i][j] = f32x4{0.f, 0.f, 0.f, 0.f};
  mfma_dbuf(At, 256, m0, Bt, 256, n0, 0, 8, As[0], As[1], Bs[0], Bs[1], tid, acc);
  const int rb = 4 * q;
  #pragma unroll
  for (int i = 0; i < 4; ++i)
    #pragma unroll
    for (int j = 0; j < 4; ++j) {
      const size_t base = (size_t)(m0 + wr * 64 + i * 16 + rb) * 4096 + n0 + wc * 64 + j * 16 + lr;
      #pragma unroll
      for (int r = 0; r < 4; ++r)
        G[base + (size_t)r * 4096] = acc[i][j][r];
    }
}

// ---------------- CF2 = wcR @ CF : bf16 out [256 o][4096 n] per batch ----------------
__global__ __launch_bounds__(256) void k_gemm_cf2(const unsigned short* __restrict__ wcRb,
    const unsigned short* __restrict__ cf3b, unsigned short* __restrict__ CF2t) {
  __shared__ unsigned short As[2][128 * ROWP];
  __shared__ unsigned short Bs[2][128 * ROWP];
  const int b = blockIdx.z;
  const int tid = threadIdx.x;
  const int o0 = blockIdx.y * 128, n0 = blockIdx.x * 128;
  const unsigned short* Bb = cf3b + (size_t)b * 4096 * 256;
  unsigned short* outb = CF2t + (size_t)b * 256 * 4096;
  const int l = tid & 63, w = tid >> 6;
  const int wr = w >> 1, wcol = w & 1;
  const int q = l >> 4, lr = l & 15;
  f32x4 acc[4][4];
  #pragma unroll
  for (int i = 0; i < 4; ++i)
    #pragma unroll
    for (int j = 0; j < 4; ++j)
      acc[i][j] = f32x4{0.f, 0.f, 0.f, 0.f};
  mfma_dbuf(wcRb, 256, o0, Bb, 256, n0, 0, 8, As[0], As[1], Bs[0], Bs[1], tid, acc);
  const int rb = 4 * q;
  #pragma unroll
  for (int i = 0; i < 4; ++i)
    #pragma unroll
    for (int j = 0; j < 4; ++j) {
      const size_t base = (size_t)(o0 + wr * 64 + i * 16 + rb) * 4096 + n0 + wcol * 64 + j * 16 + lr;
      #pragma unroll
      for (int r = 0; r < 4; ++r)
        outb[base + (size_t)r * 4096] = f2bf(acc[i][j][r]);
    }
}

// ---------------- OUT init = bc + wcL @ BF : f32 out [b][256 o][4096 m] ----------------
__global__ __launch_bounds__(256) void k_gemm_oinit(const unsigned short* __restrict__ wcLb,
    const unsigned short* __restrict__ At, const float* __restrict__ bc,
    float* __restrict__ OUT) {
  __shared__ unsigned short As[2][128 * ROWP];
  __shared__ unsigned short Bs[2][128 * ROWP];
  const int b = blockIdx.z;
  const int tid = threadIdx.x;
  const int o0 = blockIdx.y * 128, m0 = blockIdx.x * 128;
  const unsigned short* Bb = At + (size_t)b * 4096 * 256;
  float* outb = OUT + (size_t)b * 256 * 4096;
  const int l = tid & 63, w = tid >> 6;
  const int wr = w >> 1, wcol = w & 1;
  const int q = l >> 4, lr = l & 15;
  f32x4 acc[4][4];
  #pragma unroll
  for (int i = 0; i < 4; ++i)
    #pragma unroll
    for (int j = 0; j < 4; ++j)
      acc[i][j] = f32x4{0.f, 0.f, 0.f, 0.f};
  mfma_dbuf(wcLb, 256, o0, Bb, 256, m0, 0, 8, As[0], As[1], Bs[0], Bs[1], tid, acc);
  const int rb = 4 * q;
  #pragma unroll
  for (int i = 0; i < 4; ++i)
    #pragma unroll
    for (int j = 0; j < 4; ++j) {
      #pragma unroll
      for (int r = 0; r < 4; ++r) {
        const int o = o0 + wr * 64 + i * 16 + rb + r;
        outb[(size_t)o * 4096 + m0 + wcol * 64 + j * 16 + lr] = acc[i][j][r] + bc[o];
      }
    }
}

// ---------------- fused fbuild + softmax -> bf16 P ----------------
__global__ __launch_bounds__(256) void k_fsoft(const float* __restrict__ G,
    const float* __restrict__ muA, const float* __restrict__ invA,
    const float* __restrict__ muB, const float* __restrict__ invB,
    unsigned short* __restrict__ P) {
  __shared__ float redm[4];
  __shared__ float reds[4];
  const int m = ((blockIdx.x & 7) << 9) | (blockIdx.x >> 3);
  const int tid = threadIdx.x;
  const int ym = m >> 6, xm = m & 63;
  const int xn = tid & 63, ty = tid >> 6;

  const float* base[9];
  bool xok[9];
  #pragma unroll
  for (int dy = -1; dy <= 1; ++dy) {
    #pragma unroll
    for (int dx = -1; dx <= 1; ++dx) {
      const int g = (dy + 1) * 3 + (dx + 1);
      const bool rv = ((unsigned)(ym + dy) < 64u) && ((unsigned)(xm + dx) < 64u);
      const int d = dy * 64 + dx;
      base[g] = rv ? (G + (size_t)(m + d) * 4096 + d) : G;
      xok[g] = rv && ((unsigned)(xn + dx) < 64u);
    }
  }

  float acc[16];
  #pragma unroll
  for (int u = 0; u < 16; ++u) acc[u] = 0.f;

  #pragma unroll
  for (int uc = 0; uc < 4; ++uc) {
    float v[36];
    #pragma unroll
    for (int g = 0; g < 9; ++g) {
      #pragma unroll
      for (int r = 0; r < 4; ++r) {
        const int u = uc * 4 + r;
        v[g * 4 + r] = base[g][u * 256 + tid];
      }
    }
    #pragma unroll
    for (int g = 0; g < 9; ++g) {
      const int dy = g / 3 - 1;
      #pragma unroll
      for (int r = 0; r < 4; ++r) {
        const int u = uc * 4 + r;
        const bool ok = xok[g] && ((unsigned)(4 * u + ty + dy) < 64u);
        acc[u] += ok ? v[g * 4 + r] : 0.f;
      }
    }
  }

  const float s1 = 2304.f * muA[m];
  const float ia100 = invA[m] * 100.f;
  float mx = -3.4e38f;
  #pragma unroll
  for (int u = 0; u < 16; ++u) {
    const int n = tid + u * 256;
    const float lg = (acc[u] - s1 * muB[n]) * (ia100 * invB[n]);
    acc[u] = lg;
    mx = fmaxf(mx, lg);
  }
  #pragma unroll
  for (int off = 32; off; off >>= 1) mx = fmaxf(mx, __shfl_xor(mx, off));
  const int wave = tid >> 6, lane = tid & 63;
  if (lane == 0) redm[wave] = mx;
  __syncthreads();
  mx = fmaxf(fmaxf(redm[0], redm[1]), fmaxf(redm[2], redm[3]));
  float s = 0.f;
  #pragma unroll
  for (int u = 0; u < 16; ++u) {
    acc[u] = __expf(acc[u] - mx);
    s += acc[u];
  }
  #pragma unroll
  for (int off = 32; off; off >>= 1) s += __shfl_xor(s, off);
  if (lane == 0) reds[wave] = s;
  __syncthreads();
  s = reds[0] + reds[1] + reds[2] + reds[3];
  const float inv = 1.f / s;
  unsigned short* row = P + (size_t)m * 4096;
  #pragma unroll
  for (int u = 0; u < 16; ++u)
    row[tid + u * 256] = f2bf(acc[u] * inv);
}

// ---------------- OUT += CF2 x P^T : split-K, atomics into d_out ----------------
__global__ __launch_bounds__(256) void k_pv(const unsigned short* __restrict__ CF2t,
    const unsigned short* __restrict__ P, float* __restrict__ OUT) {
  __shared__ unsigned short As[2][128 * ROWP];
  __shared__ unsigned short Bs[2][128 * ROWP];
  const int tid = threadIdx.x;
  const int c0 = blockIdx.y * 128, mb0 = blockIdx.x * 128;
  const int kbase = blockIdx.z * 512;
  const int l = tid & 63, w = tid >> 6;
  const int wr = w >> 1, wc = w & 1;
  const int q = l >> 4, lr = l & 15;
  f32x4 acc[4][4];
  #pragma unroll
  for (int i = 0; i < 4; ++i)
    #pragma unroll
    for (int j = 0; j < 4; ++j)
      acc[i][j] = f32x4{0.f, 0.f, 0.f, 0.f};
  mfma_dbuf(CF2t, 4096, c0, P, 4096, mb0, kbase, 16, As[0], As[1], Bs[0], Bs[1], tid, acc);
  const int rb = 4 * q;
  #pragma unroll
  for (int i = 0; i < 4; ++i)
    #pragma unroll
    for (int j = 0; j < 4; ++j) {
      #pragma unroll
      for (int r = 0; r < 4; ++r) {
        const size_t o = (size_t)(c0 + wr * 64 + i * 16 + rb + r) * 4096 + mb0 + wc * 64 + j * 16 + lr;
        atomicAdd(&OUT[o], acc[i][j][r]);
      }
    }
}

extern "C" void kernel_launch(void* const* d_in, const int* in_sizes, int n_in,
                              void* d_out, int out_size, void* d_ws, size_t ws_size,
                              hipStream_t stream) {
  const float* block_fea = (const float*)d_in[0];
  const float* spp       = (const float*)d_in[1];
  const float* click     = (const float*)d_in[2];
  const float* w1 = (const float*)d_in[3];
  const float* b1 = (const float*)d_in[4];
  const float* w2 = (const float*)d_in[5];
  const float* b2 = (const float*)d_in[6];
  const float* w3 = (const float*)d_in[7];
  const float* b3 = (const float*)d_in[8];
  const float* wc = (const float*)d_in[9];
  const float* bc = (const float*)d_in[10];
  float* out = (float*)d_out;

  float* ws = (float*)d_ws;
  const size_t M1 = 1024 * 1024;
  float* cf2  = ws;                          // 8M f (dead before G written)
  float* G    = ws + 256;                    // 16M f, guard slack both sides
  unsigned short* Pb   = (unsigned short*)(ws + 17 * M1);  // 16M ushort
  unsigned short* At   = (unsigned short*)(ws + 25 * M1);  // 4M ushort
  unsigned short* Bt   = (unsigned short*)(ws + 27 * M1);  // 4M ushort
  unsigned short* CF3b = (unsigned short*)(ws + 29 * M1);  // 4M ushort
  unsigned short* CF2t = (unsigned short*)(ws + 31 * M1);  // 8M ushort
  unsigned short* wcLb = (unsigned short*)(ws + 35 * M1);  // 64K ushort
  unsigned short* wcRb = wcLb + 65536;                     // 64K ushort
  float* SA   = ws + 36 * M1;
  float* QA   = SA + 16384;
  float* SB   = QA + 16384;
  float* QB   = SB + 16384;
  float* muA  = QB + 16384;
  float* invA = muA + 16384;
  float* muB  = invA + 16384;
  float* invB = muB + 16384;

  // zero stats (SA..QB = 65536 floats)
  k_zero<<<dim3(64), 256, 0, stream>>>(SA);
  k_wsplit<<<dim3(512), 256, 0, stream>>>(wc, wcLb, wcRb);
  k_pyr1<<<dim3(1024, 4), 128, 0, stream>>>(click, w1, b1, w2, b2, cf2);
  k_pyr2<<<dim3(256, 4), 256, 0, stream>>>(cf2, w3, b3, CF3b);
  k_tcast<<<dim3(64, 4, 4), 256, 0, stream>>>(block_fea, At, 256, 4096,
                                              (size_t)256 * 4096, (size_t)4096 * 256, SA, QA);
  k_tcast<<<dim3(64, 4, 4), 256, 0, stream>>>(spp, Bt, 256, 4096,
                                              (size_t)256 * 4096, (size_t)4096 * 256, SB, QB);
  k_stats9<<<dim3(16, 4), 256, 0, stream>>>(SA, QA, SB, QB, muA, invA, muB, invB);
  k_gemm_cf2<<<dim3(32, 2, 4), 256, 0, stream>>>(wcRb, CF3b, CF2t);
  k_gemm_oinit<<<dim3(32, 2, 4), 256, 0, stream>>>(wcLb, At, bc, out);

  for (int b = 0; b < 4; ++b) {
    const unsigned short* Atb = At + (size_t)b * 4096 * 256;
    const unsigned short* Btb = Bt + (size_t)b * 4096 * 256;
    k_gemm_g<<<dim3(32, 32), 256, 0, stream>>>(Atb, Btb, G);
    k_fsoft<<<dim3(4096), 256, 0, stream>>>(G, muA + b * 4096, invA + b * 4096,
                                            muB + b * 4096, invB + b * 4096, Pb);
    k_pv<<<dim3(32, 2, 8), 256, 0, stream>>>(CF2t + (size_t)b * 256 * 4096, Pb,
                                             out + (size_t)b * 256 * 4096);
  }
}